// Round 11
// baseline (217.090 us; speedup 1.0000x reference)
//
#include <hip/hip_runtime.h>

typedef unsigned short ushort_t;
typedef __attribute__((ext_vector_type(8))) unsigned short ushort8;
typedef __attribute__((ext_vector_type(4))) unsigned short ushortv4;
typedef __attribute__((ext_vector_type(8))) __bf16 bf16x8;
typedef __attribute__((ext_vector_type(4))) float f32x4;

#define BATCH   2
#define SEQLEN  2048
#define BL      4096
#define DMODEL  1024
#define DINNER  2048
#define DSTATE  128
#define NHEADS  16
#define DXBC    2304
#define DPROJ   4368
#define NPAD    4608        // padded to multiple of 256 for 256-wide GEMM
#define EPSF    1e-5f
#define QCH     128
#define NCH     16          // SEQLEN / QCH
#define BH      32          // BATCH * NHEADS

// swizzled byte offset within a 256-byte LDS row (bf16, 128 cols)
#define SWZ(row, colbyte) ((colbyte) ^ (((row) & 7) << 4))

#define GLDS(gp, lp) __builtin_amdgcn_global_load_lds( \
    (const __attribute__((address_space(1))) void*)(gp), \
    (__attribute__((address_space(3))) void*)(lp), 16, 0, 0)

__device__ __forceinline__ float bf2f(ushort_t h) {
    unsigned int u = ((unsigned int)h) << 16;
    float f; __builtin_memcpy(&f, &u, 4); return f;
}
__device__ __forceinline__ ushort_t f2bf(float f) {
    unsigned int u; __builtin_memcpy(&u, &f, 4);
    unsigned int r = u + 0x7fffu + ((u >> 16) & 1u);
    return (ushort_t)(r >> 16);
}
__device__ __forceinline__ float siluf(float x) { return x / (1.f + expf(-x)); }
__device__ __forceinline__ float softplusf(float x) { return (x > 20.f) ? x : log1pf(expf(x)); }

// ---------------- LayerNorm + cast to bf16 ----------------
__global__ __launch_bounds__(256) void ln_kernel(const float* __restrict__ x,
        const float* __restrict__ w, const float* __restrict__ b, ushort_t* __restrict__ xn) {
    int r = blockIdx.x, t = threadIdx.x;
    const float* xr = x + (size_t)r * DMODEL;
    float4 v = *(const float4*)&xr[t * 4];
    float s  = v.x + v.y + v.z + v.w;
    float sq = v.x*v.x + v.y*v.y + v.z*v.z + v.w*v.w;
    __shared__ float red[8];
    #pragma unroll
    for (int m = 32; m >= 1; m >>= 1) { s += __shfl_xor(s, m, 64); sq += __shfl_xor(sq, m, 64); }
    int wv = t >> 6;
    if ((t & 63) == 0) { red[wv] = s; red[4 + wv] = sq; }
    __syncthreads();
    s  = red[0] + red[1] + red[2] + red[3];
    sq = red[4] + red[5] + red[6] + red[7];
    float mu  = s * (1.f / DMODEL);
    float var = sq * (1.f / DMODEL) - mu * mu;
    float inv = rsqrtf(var + EPSF);
    float4 wv4 = *(const float4*)&w[t * 4];
    float4 bv4 = *(const float4*)&b[t * 4];
    ushortv4 o;
    o[0] = f2bf((v.x - mu) * inv * wv4.x + bv4.x);
    o[1] = f2bf((v.y - mu) * inv * wv4.y + bv4.y);
    o[2] = f2bf((v.z - mu) * inv * wv4.z + bv4.z);
    o[3] = f2bf((v.w - mu) * inv * wv4.w + bv4.w);
    *(ushortv4*)&xn[(size_t)r * DMODEL + t * 4] = o;
}

// ---------------- transpose + cast f32[K][N] -> bf16[Npad][K] ----------------
__global__ __launch_bounds__(256) void transpose_cast(const float* __restrict__ W,
        ushort_t* __restrict__ WT, int K, int N) {
    __shared__ float tile[32][33];
    int n0 = blockIdx.x * 32, k0 = blockIdx.y * 32;
    int tx = threadIdx.x & 31, ty = threadIdx.x >> 5;
    #pragma unroll
    for (int i = 0; i < 32; i += 8) {
        int n = n0 + tx;
        tile[ty + i][tx] = (n < N) ? W[(size_t)(k0 + ty + i) * N + n] : 0.f;
    }
    __syncthreads();
    #pragma unroll
    for (int i = 0; i < 32; i += 8) {
        WT[(size_t)(n0 + ty + i) * K + k0 + tx] = f2bf(tile[tx][ty + i]);
    }
}

// ---------------- conv weight transpose: wtr[k][c] = conv_w[c][k] ----------------
__global__ __launch_bounds__(256) void convw_tr(const float* __restrict__ w,
        float* __restrict__ wt) {
    int c = blockIdx.x * 256 + threadIdx.x;
    if (c < DXBC) {
        float4 v = *(const float4*)&w[c * 4];
        wt[0 * DXBC + c] = v.x;
        wt[1 * DXBC + c] = v.y;
        wt[2 * DXBC + c] = v.z;
        wt[3 * DXBC + c] = v.w;
    }
}

// ---------------- 256x256 GEMM (bf16 out): C = A[M][K] @ BT[N][K]^T ----------------
// 512 threads (2x4 waves), wave = 128x64 output. BK=64, double-buffered 128KB LDS.
// Register-reuse order: per k-half load 4 B-frags once, reuse across 8 M-frags.
// LDS k-chunk XOR swizzle (row&7)<<4, source pre-swizzled (rule #21 both-sides).
__global__ __launch_bounds__(512) void gemm256_bt(const ushort_t* __restrict__ A,
        const ushort_t* __restrict__ BT, ushort_t* __restrict__ C,
        int K, int ldc, int nbx) {
    const int tid = threadIdx.x;
    const int nwg = gridDim.x;
    const int cpx = nwg >> 3;
    const int lid = (blockIdx.x & 7) * cpx + (blockIdx.x >> 3);
    const int m0 = (lid / nbx) * 256, n0 = (lid % nbx) * 256;
    __shared__ ushort_t As[2][256 * 64];   // 32 KB per slot
    __shared__ ushort_t Bs[2][256 * 64];
    const int lane = tid & 63, wid = tid >> 6;
    const int l8 = lane >> 3, c8 = lane & 7;
    const int selm = (c8 ^ l8) * 8;                     // pre-swizzled k-chunk
    const ushort_t* aB = A  + (size_t)(m0 + wid * 8 + l8) * K + selm;
    const ushort_t* bB = BT + (size_t)(n0 + wid * 8 + l8) * K + selm;
    const int wm2 = wid >> 2, wn4 = wid & 3;
    const int fr = lane & 15, ko2 = (lane >> 4) * 16;   // k byte offset bits 4-5
    f32x4 acc[8][4];
    #pragma unroll
    for (int i = 0; i < 8; i++)
        #pragma unroll
        for (int j = 0; j < 4; j++) acc[i][j] = (f32x4){0.f, 0.f, 0.f, 0.f};
    const int nt = K >> 6;
    // stage one K-tile (A and B, 8 GLDS/thread)
    #define ST256(slot, kt) do { \
        const size_t kof = (size_t)(kt) * 64; \
        _Pragma("unroll") \
        for (int q = 0; q < 4; q++) { \
            GLDS(aB + (size_t)q * 64 * K + kof, &As[slot][(q * 64 + wid * 8) * 64]); \
            GLDS(bB + (size_t)q * 64 * K + kof, &Bs[slot][(q * 64 + wid * 8) * 64]); \
        } \
    } while (0)
    ST256(0, 0);
    asm volatile("s_waitcnt vmcnt(0)" ::: "memory");
    __builtin_amdgcn_s_barrier();
    int cur = 0;
    for (int t = 0; t < nt; ++t) {
        if (t + 1 < nt) ST256(cur ^ 1, t + 1);
        #pragma unroll
        for (int kh = 0; kh < 2; kh++) {
            bf16x8 bq[4];
            #pragma unroll
            for (int nj = 0; nj < 4; nj++) {
                int rn = wn4 * 64 + nj * 16 + fr;
                int kb = (kh * 64 + ko2) ^ ((rn & 7) << 4);
                bq[nj] = *(const bf16x8*)((const char*)&Bs[cur][0] + rn * 128 + kb);
            }
            #pragma unroll
            for (int mi = 0; mi < 8; mi++) {
                int row = wm2 * 128 + mi * 16 + fr;
                int kb = (kh * 64 + ko2) ^ ((row & 7) << 4);
                bf16x8 a = *(const bf16x8*)((const char*)&As[cur][0] + row * 128 + kb);
                #pragma unroll
                for (int nj = 0; nj < 4; nj++)
                    acc[mi][nj] = __builtin_amdgcn_mfma_f32_16x16x32_bf16(a, bq[nj], acc[mi][nj], 0, 0, 0);
            }
        }
        asm volatile("s_waitcnt vmcnt(0)" ::: "memory");  // next tile landed (issued ~1 tile ago)
        __builtin_amdgcn_s_barrier();
        cur ^= 1;
    }
    const int r0 = (lane >> 4) * 4;
    #pragma unroll
    for (int mi = 0; mi < 8; mi++)
        #pragma unroll
        for (int nj = 0; nj < 4; nj++)
            #pragma unroll
            for (int r = 0; r < 4; r++) {
                int m = m0 + wm2 * 128 + mi * 16 + r0 + r;
                int n = n0 + wn4 * 64 + nj * 16 + fr;
                C[(size_t)m * ldc + n] = f2bf(acc[mi][nj][r]);
            }
    #undef ST256
}

// ---------------- 128x128 GEMM (f32 out + resid) — round-10 proven ----------------
__global__ __launch_bounds__(256) void gemm_bt(const ushort_t* __restrict__ A,
        const ushort_t* __restrict__ BT, float* __restrict__ C,
        const float* __restrict__ resid, int K, int ldc, int nbx) {
    const int tid = threadIdx.x;
    const int nwg = gridDim.x;
    const int cpx = nwg >> 3;
    const int lid = (blockIdx.x & 7) * cpx + (blockIdx.x >> 3);
    const int m0 = (lid / nbx) * 128, n0 = (lid % nbx) * 128;
    __shared__ ushort_t As[3][128 * 32];
    __shared__ ushort_t Bs[3][128 * 32];
    const int lane = tid & 63, wave = tid >> 6;
    const int wrow = wave * 32;
    const int srow = lane >> 2;
    const int selm = ((lane & 3) ^ (srow & 3)) * 8;
    const ushort_t* ag0 = A  + (size_t)(m0 + wrow + srow) * K + selm;
    const ushort_t* ag1 = ag0 + (size_t)16 * K;
    const ushort_t* bg0 = BT + (size_t)(n0 + wrow + srow) * K + selm;
    const ushort_t* bg1 = bg0 + (size_t)16 * K;
    const int wm = (wave >> 1) * 64, wn = (wave & 1) * 64;
    const int fr = lane & 15, ko = (lane >> 4) * 8;
    f32x4 acc[4][4];
    #pragma unroll
    for (int i = 0; i < 4; i++)
        #pragma unroll
        for (int j = 0; j < 4; j++) acc[i][j] = (f32x4){0.f, 0.f, 0.f, 0.f};
    const int nt = K >> 5;
    #pragma unroll
    for (int t = 0; t < 3; t++) {
        const size_t kof = (size_t)t * 32;
        GLDS(ag0 + kof, &As[t][wrow * 32]);
        GLDS(ag1 + kof, &As[t][(wrow + 16) * 32]);
        GLDS(bg0 + kof, &Bs[t][wrow * 32]);
        GLDS(bg1 + kof, &Bs[t][(wrow + 16) * 32]);
    }
    asm volatile("s_waitcnt vmcnt(8)" ::: "memory");
    __builtin_amdgcn_s_barrier();
    int cur = 0;
    for (int t = 0; t < nt; ++t) {
        if (t + 2 < nt) {
            int nb = cur + 2; if (nb >= 3) nb -= 3;
            const size_t kof = (size_t)(t + 2) * 32;
            GLDS(ag0 + kof, &As[nb][wrow * 32]);
            GLDS(ag1 + kof, &As[nb][(wrow + 16) * 32]);
            GLDS(bg0 + kof, &Bs[nb][wrow * 32]);
            GLDS(bg1 + kof, &Bs[nb][(wrow + 16) * 32]);
        }
        bf16x8 af[4], bfr[4];
        #pragma unroll
        for (int i = 0; i < 4; i++) {
            int row = wm + i * 16 + fr;
            af[i] = *(const bf16x8*)((const char*)&As[cur][0] + row * 64
                                     + ((ko * 2) ^ ((row & 3) << 4)));
        }
        #pragma unroll
        for (int j = 0; j < 4; j++) {
            int row = wn + j * 16 + fr;
            bfr[j] = *(const bf16x8*)((const char*)&Bs[cur][0] + row * 64
                                      + ((ko * 2) ^ ((row & 3) << 4)));
        }
        #pragma unroll
        for (int i = 0; i < 4; i++)
            #pragma unroll
            for (int j = 0; j < 4; j++)
                acc[i][j] = __builtin_amdgcn_mfma_f32_16x16x32_bf16(af[i], bfr[j], acc[i][j], 0, 0, 0);
        if (t + 2 < nt) asm volatile("s_waitcnt vmcnt(4)" ::: "memory");
        else            asm volatile("s_waitcnt vmcnt(0)" ::: "memory");
        __builtin_amdgcn_s_barrier();
        cur = (cur == 2) ? 0 : cur + 1;
    }
    const int r0 = (lane >> 4) * 4;
    #pragma unroll
    for (int i = 0; i < 4; i++)
        #pragma unroll
        for (int j = 0; j < 4; j++)
            #pragma unroll
            for (int r = 0; r < 4; r++) {
                int m = m0 + wm + i * 16 + r0 + r;
                int n = n0 + wn + j * 16 + fr;
                float v = acc[i][j][r];
                if (resid) v += resid[(size_t)m * ldc + n];
                C[(size_t)m * ldc + n] = v;
            }
}

// ---------------- conv4 + SiLU + split + dt/dtA (bf16 zxb, transposed weights) ----------------
__global__ __launch_bounds__(256) void conv_kernel(const ushort_t* __restrict__ zxb,
        const float* __restrict__ wtr, const float* __restrict__ conv_b,
        const float* __restrict__ dt_bias, const float* __restrict__ A_log,
        ushort_t* __restrict__ xcv, ushort_t* __restrict__ Bcg, ushort_t* __restrict__ Ccg,
        float* __restrict__ dtv, float* __restrict__ dta) {
    int bid = blockIdx.x;
    int l = bid & (SEQLEN - 1);
    int tid = threadIdx.x;
    const ushort_t* rowp = zxb + (size_t)bid * NPAD;
    #pragma unroll 1
    for (int u = tid; u < DXBC / 8; u += 256) {
        int c0 = u * 8;
        float acc[8];
        {
            float4 b0 = *(const float4*)&conv_b[c0];
            float4 b1 = *(const float4*)&conv_b[c0 + 4];
            acc[0] = b0.x; acc[1] = b0.y; acc[2] = b0.z; acc[3] = b0.w;
            acc[4] = b1.x; acc[5] = b1.y; acc[6] = b1.z; acc[7] = b1.w;
        }
        #pragma unroll
        for (int k = 0; k < 4; k++) {
            int ll = l - 3 + k;
            if (ll >= 0) {
                ushort8 xv = *(const ushort8*)&rowp[(ptrdiff_t)(k - 3) * NPAD + DINNER + c0];
                float4 w0 = *(const float4*)&wtr[k * DXBC + c0];
                float4 w1 = *(const float4*)&wtr[k * DXBC + c0 + 4];
                acc[0] += bf2f((ushort_t)xv[0]) * w0.x;
                acc[1] += bf2f((ushort_t)xv[1]) * w0.y;
                acc[2] += bf2f((ushort_t)xv[2]) * w0.z;
                acc[3] += bf2f((ushort_t)xv[3]) * w0.w;
                acc[4] += bf2f((ushort_t)xv[4]) * w1.x;
                acc[5] += bf2f((ushort_t)xv[5]) * w1.y;
                acc[6] += bf2f((ushort_t)xv[6]) * w1.z;
                acc[7] += bf2f((ushort_t)xv[7]) * w1.w;
            }
        }
        ushort8 o;
        #pragma unroll
        for (int e = 0; e < 8; e++) o[e] = f2bf(siluf(acc[e]));
        if (c0 < DINNER)                *(ushort8*)&xcv[(size_t)bid * DINNER + c0] = o;
        else if (c0 < DINNER + DSTATE)  *(ushort8*)&Bcg[(size_t)bid * DSTATE + (c0 - DINNER)] = o;
        else                            *(ushort8*)&Ccg[(size_t)bid * DSTATE + (c0 - DINNER - DSTATE)] = o;
    }
    if (tid < NHEADS) {
        float raw = bf2f(rowp[DINNER + DXBC + tid]) + dt_bias[tid];
        float dt = softplusf(raw);
        float A = -expf(A_log[tid]);
        dtv[(size_t)bid * NHEADS + tid] = dt;
        dta[(size_t)bid * NHEADS + tid] = dt * A;
    }
}

// ---------------- per-chunk cumulative sums of dt*A ----------------
__global__ __launch_bounds__(128) void cumsum_kernel(const float* __restrict__ dta,
        const float* __restrict__ dtv, float* __restrict__ cabuf, float* __restrict__ expca,
        float* __restrict__ wbuf, float* __restrict__ dtbuf, float* __restrict__ dtot) {
    const int c = blockIdx.x, h = blockIdx.y, b = blockIdx.z;
    const int bh = b * NHEADS + h;
    const int j = threadIdx.x;
    const size_t row = (size_t)b * SEQLEN + c * QCH + j;
    float v  = dta[row * NHEADS + h];
    float dt = dtv[row * NHEADS + h];
    float pv = v;
    #pragma unroll
    for (int off = 1; off < 64; off <<= 1) {
        float u = __shfl_up(pv, off, 64);
        if ((j & 63) >= off) pv += u;
    }
    __shared__ float wsum[2];
    if ((j & 63) == 63) wsum[j >> 6] = pv;
    __syncthreads();
    float tot = wsum[0] + wsum[1];
    if (j >= 64) pv += wsum[0];
    const size_t idx = ((size_t)bh * NCH + c) * QCH + j;
    cabuf[idx] = pv;
    expca[idx] = expf(pv);
    wbuf[idx]  = expf(tot - pv) * dt;
    dtbuf[idx] = dt;
    if (j == 0) dtot[bh * NCH + c] = expf(tot);
}

// ---------------- chunk end-state: states[bh][c][p][n] = sum_j w_j x[j][p] B[j][n] (bf16 out) ----------------
__global__ __launch_bounds__(256) void chunkstate_kernel(const ushort_t* __restrict__ xcv,
        const ushort_t* __restrict__ Bcg, const float* __restrict__ wbuf,
        ushort_t* __restrict__ states) {
    const int c = blockIdx.x, h = blockIdx.y, b = blockIdx.z;
    const int bh = b * NHEADS + h;
    const int tid = threadIdx.x;
    __shared__ ushort_t Xt[128 * 128];     // [p][j] swizzled
    __shared__ ushort_t Bt[128 * 128];     // [n][j] swizzled
    __shared__ float wsh[QCH];
    if (tid < QCH) wsh[tid] = wbuf[((size_t)bh * NCH + c) * QCH + tid];
    __syncthreads();
    const size_t row0 = (size_t)b * SEQLEN + c * QCH;
    {
        const int f = tid & 127;
        const int jh = (tid >> 7) * 64;
        const ushort_t* xsrc = xcv + (row0 + jh) * DINNER + h * 128 + f;
        const ushort_t* bsrc = Bcg + (row0 + jh) * DSTATE + f;
        char* xrow = (char*)Xt + f * 256;
        char* brow = (char*)Bt + f * 256;
        #pragma unroll 2
        for (int e8 = 0; e8 < 8; e8++) {
            ushort8 tx, tb;
            #pragma unroll
            for (int e = 0; e < 8; e++) {
                int j = e8 * 8 + e;
                tx[e] = xsrc[(size_t)j * DINNER];
                tb[e] = f2bf(bf2f(bsrc[(size_t)j * DSTATE]) * wsh[jh + j]);
            }
            int cb = (jh + e8 * 8) * 2;
            *(ushort8*)(xrow + SWZ(f, cb)) = tx;
            *(ushort8*)(brow + SWZ(f, cb)) = tb;
        }
    }
    __syncthreads();
    const int lane = tid & 63, wave = tid >> 6;
    const int wp = (wave >> 1) * 64, wn = (wave & 1) * 64;
    const int fr = lane & 15, ko = (lane >> 4) * 8;
    f32x4 acc[4][4];
    #pragma unroll
    for (int i = 0; i < 4; i++)
        #pragma unroll
        for (int j = 0; j < 4; j++) acc[i][j] = (f32x4){0.f, 0.f, 0.f, 0.f};
    for (int k0 = 0; k0 < 128; k0 += 32) {
        bf16x8 af[4], bfr[4];
        #pragma unroll
        for (int i = 0; i < 4; i++) {
            int rp = wp + i * 16 + fr;
            af[i] = *(const bf16x8*)((const char*)Xt + rp * 256 + SWZ(rp, (k0 + ko) * 2));
        }
        #pragma unroll
        for (int j = 0; j < 4; j++) {
            int rn = wn + j * 16 + fr;
            bfr[j] = *(const bf16x8*)((const char*)Bt + rn * 256 + SWZ(rn, (k0 + ko) * 2));
        }
        #pragma unroll
        for (int i = 0; i < 4; i++)
            #pragma unroll
            for (int j = 0; j < 4; j++)
                acc[i][j] = __builtin_amdgcn_mfma_f32_16x16x32_bf16(af[i], bfr[j], acc[i][j], 0, 0, 0);
    }
    const int r0 = (lane >> 4) * 4;
    ushort_t* outp = states + ((size_t)bh * NCH + c) * 16384;
    #pragma unroll
    for (int i = 0; i < 4; i++)
        #pragma unroll
        for (int j = 0; j < 4; j++)
            #pragma unroll
            for (int r = 0; r < 4; r++)
                outp[(wp + i * 16 + r0 + r) * 128 + wn + j * 16 + fr] = f2bf(acc[i][j][r]);
}

// ---------------- inter-chunk state scan (in place, bf16 storage, f32 accum) ----------------
__global__ __launch_bounds__(256) void statescan_kernel(ushort_t* __restrict__ states,
        const float* __restrict__ dtot) {
    const int pseg = blockIdx.x, bh = blockIdx.y;
    const int tid = threadIdx.x;
    const int p = pseg * 8 + (tid >> 5);
    const int n4 = (tid & 31) * 4;
    ushort_t* base = states + (size_t)bh * NCH * 16384 + p * 128 + n4;
    const float* dtp = dtot + bh * NCH;
    float r0 = 0.f, r1 = 0.f, r2 = 0.f, r3 = 0.f;
    #pragma unroll 1
    for (int c = 0; c < NCH; c++) {
        ushortv4* ptr = (ushortv4*)(base + (size_t)c * 16384);
        ushortv4 cs = *ptr;
        ushortv4 o;
        o[0] = f2bf(r0); o[1] = f2bf(r1); o[2] = f2bf(r2); o[3] = f2bf(r3);
        *ptr = o;
        float d = dtp[c];
        r0 = r0 * d + bf2f(cs[0]);
        r1 = r1 * d + bf2f(cs[1]);
        r2 = r2 * d + bf2f(cs[2]);
        r3 = r3 * d + bf2f(cs[3]);
    }
}

// ---------------- chunk output: y = exp(ca)*(C @ S_init) + (mask(CB^T) masked-decay) @ X ----------------
__global__ __launch_bounds__(256) void chunkout_kernel(const ushort_t* __restrict__ xcv,
        const ushort_t* __restrict__ Bcg, const ushort_t* __restrict__ Ccg,
        const ushort_t* __restrict__ states, const float* __restrict__ cabuf,
        const float* __restrict__ expca, const float* __restrict__ dtbuf,
        const float* __restrict__ Dvec, ushort_t* __restrict__ yv) {
    const int c = blockIdx.x, h = blockIdx.y, b = blockIdx.z;
    const int bh = b * NHEADS + h;
    const int tid = threadIdx.x;
    __shared__ ushort_t R1[128 * 128];   // ST -> B -> P
    __shared__ ushort_t R2[128 * 128];   // C -> Xt
    __shared__ float cash[QCH], dtsh[QCH], exsh[QCH];
    const size_t aidx = ((size_t)bh * NCH + c) * QCH;
    if (tid < QCH) {
        cash[tid] = cabuf[aidx + tid];
        dtsh[tid] = dtbuf[aidx + tid];
        exsh[tid] = expca[aidx + tid];
    }
    const size_t row0 = (size_t)b * SEQLEN + c * QCH;
    {
        const ushort_t* sp = states + ((size_t)bh * NCH + c) * 16384;
        #pragma unroll
        for (int it = 0; it < 8; it++) {
            int g = tid + it * 256;
            int r = g >> 4, n8 = (g & 15) * 8;
            ushort8 vc = *(const ushort8*)&Ccg[(row0 + r) * DSTATE + n8];
            ushort8 vs = *(const ushort8*)&sp[r * 128 + n8];
            int cb = n8 * 2;
            *(ushort8*)((char*)R2 + r * 256 + SWZ(r, cb)) = vc;
            *(ushort8*)((char*)R1 + r * 256 + SWZ(r, cb)) = vs;
        }
    }
    __syncthreads();
    const int lane = tid & 63, wave = tid >> 6;
    const int fr = lane & 15, ko = (lane >> 4) * 8, r0 = (lane >> 4) * 4;
    const int wty = (wave >> 1) * 64, wpy = (wave & 1) * 64;
    f32x4 y_[4][4];
    #pragma unroll
    for (int i = 0; i < 4; i++)
        #pragma unroll
        for (int j = 0; j < 4; j++) y_[i][j] = (f32x4){0.f, 0.f, 0.f, 0.f};
    for (int k0 = 0; k0 < 128; k0 += 32) {
        bf16x8 af[4], bfr[4];
        #pragma unroll
        for (int i = 0; i < 4; i++) {
            int rt = wty + i * 16 + fr;
            af[i] = *(const bf16x8*)((const char*)R2 + rt * 256 + SWZ(rt, (k0 + ko) * 2));
        }
        #pragma unroll
        for (int j = 0; j < 4; j++) {
            int rp = wpy + j * 16 + fr;
            bfr[j] = *(const bf16x8*)((const char*)R1 + rp * 256 + SWZ(rp, (k0 + ko) * 2));
        }
        #pragma unroll
        for (int i = 0; i < 4; i++)
            #pragma unroll
            for (int j = 0; j < 4; j++)
                y_[i][j] = __builtin_amdgcn_mfma_f32_16x16x32_bf16(af[i], bfr[j], y_[i][j], 0, 0, 0);
    }
    #pragma unroll
    for (int i = 0; i < 4; i++)
        #pragma unroll
        for (int r = 0; r < 4; r++) {
            float sc = exsh[wty + i * 16 + r0 + r];
            #pragma unroll
            for (int j = 0; j < 4; j++) y_[i][j][r] *= sc;
        }
    __syncthreads();
    #pragma unroll
    for (int it = 0; it < 8; it++) {
        int g = tid + it * 256;
        int r = g >> 4, n8 = (g & 15) * 8;
        ushort8 vb = *(const ushort8*)&Bcg[(row0 + r) * DSTATE + n8];
        *(ushort8*)((char*)R1 + r * 256 + SWZ(r, n8 * 2)) = vb;
    }
    __syncthreads();
    const int wj = (wave >> 1) * 64, wt = (wave & 1) * 64;
    f32x4 g_[4][4];
    #pragma unroll
    for (int i = 0; i < 4; i++)
        #pragma unroll
        for (int t = 0; t < 4; t++) g_[i][t] = (f32x4){0.f, 0.f, 0.f, 0.f};
    if (!(wj == 64 && wt == 0)) {
        for (int k0 = 0; k0 < 128; k0 += 32) {
            bf16x8 af[4], bfr[4];
            #pragma unroll
            for (int i = 0; i < 4; i++) {
                int rj = wj + i * 16 + fr;
                af[i] = *(const bf16x8*)((const char*)R1 + rj * 256 + SWZ(rj, (k0 + ko) * 2));
            }
            #pragma unroll
            for (int t = 0; t < 4; t++) {
                int rt = wt + t * 16 + fr;
                bfr[t] = *(const bf16x8*)((const char*)R2 + rt * 256 + SWZ(rt, (k0 + ko) * 2));
            }
            #pragma unroll
            for (int i = 0; i < 4; i++)
                #pragma unroll
                for (int t = 0; t < 4; t++)
                    g_[i][t] = __builtin_amdgcn_mfma_f32_16x16x32_bf16(af[i], bfr[t], g_[i][t], 0, 0, 0);
        }
    }
    __syncthreads();
    {
        const float Dh = Dvec[h];
        #pragma unroll
        for (int i = 0; i < 4; i++) {
            #pragma unroll
            for (int t = 0; t < 4; t++) {
                int tt = wt + t * 16 + fr;
                int jj0 = wj + i * 16 + r0;
                ushortv4 pk;
                #pragma unroll
                for (int r = 0; r < 4; r++) {
                    int jj = jj0 + r;
                    float val = 0.f;
                    if (jj <= tt) {
                        val = g_[i][t][r] * expf(cash[tt] - cash[jj]) * dtsh[jj];
                        if (jj == tt) val += Dh;
                    }
                    pk[r] = f2bf(val);
                }
                *(ushortv4*)((char*)R1 + tt * 256 + SWZ(tt, jj0 * 2)) = pk;
            }
        }
        const int f = tid & 127;
        const int jh = (tid >> 7) * 64;
        const ushort_t* xsrc = xcv + (row0 + jh) * DINNER + h * 128 + f;
        char* xrow = (char*)R2 + f * 256;
        #pragma unroll 2
        for (int e8 = 0; e8 < 8; e8++) {
            ushort8 tx;
            #pragma unroll
            for (int e = 0; e < 8; e++) tx[e] = xsrc[(size_t)(e8 * 8 + e) * DINNER];
            int cb = (jh + e8 * 8) * 2;
            *(ushort8*)(xrow + SWZ(f, cb)) = tx;
        }
    }
    __syncthreads();
    const int kmax = wty + 64;
    for (int k0 = 0; k0 < kmax; k0 += 32) {
        bf16x8 af[4], bfr[4];
        #pragma unroll
        for (int i = 0; i < 4; i++) {
            int rt = wty + i * 16 + fr;
            af[i] = *(const bf16x8*)((const char*)R1 + rt * 256 + SWZ(rt, (k0 + ko) * 2));
        }
        #pragma unroll
        for (int j = 0; j < 4; j++) {
            int rp = wpy + j * 16 + fr;
            bfr[j] = *(const bf16x8*)((const char*)R2 + rp * 256 + SWZ(rp, (k0 + ko) * 2));
        }
        #pragma unroll
        for (int i = 0; i < 4; i++)
            #pragma unroll
            for (int j = 0; j < 4; j++)
                y_[i][j] = __builtin_amdgcn_mfma_f32_16x16x32_bf16(af[i], bfr[j], y_[i][j], 0, 0, 0);
    }
    #pragma unroll
    for (int i = 0; i < 4; i++)
        #pragma unroll
        for (int j = 0; j < 4; j++)
            #pragma unroll
            for (int r = 0; r < 4; r++) {
                int t = wty + i * 16 + r0 + r;
                int p = wpy + j * 16 + fr;
                yv[(row0 + t) * DINNER + h * 128 + p] = f2bf(y_[i][j][r]);
            }
}

// ---------------- gate (y * silu(z)) + RMSNorm -> bf16 (z from bf16 zxb) ----------------
__global__ __launch_bounds__(256) void gate_rms(const ushort_t* __restrict__ yv,
        const ushort_t* __restrict__ zxb, const float* __restrict__ rms_w,
        ushort_t* __restrict__ ynorm) {
    int r = blockIdx.x, t = threadIdx.x;
    const ushort_t* yr = yv + (size_t)r * DINNER;
    const ushort_t* zr = zxb + (size_t)r * NPAD;
    ushort8 y8 = *(const ushort8*)&yr[t * 8];
    ushort8 z8 = *(const ushort8*)&zr[t * 8];
    float g[8];
    #pragma unroll
    for (int j = 0; j < 8; j++)
        g[j] = bf2f((ushort_t)y8[j]) * siluf(bf2f((ushort_t)z8[j]));
    float sq = 0.f;
    #pragma unroll
    for (int j = 0; j < 8; j++) sq += g[j] * g[j];
    __shared__ float red[4];
    #pragma unroll
    for (int m = 32; m >= 1; m >>= 1) sq += __shfl_xor(sq, m, 64);
    int wv = t >> 6;
    if ((t & 63) == 0) red[wv] = sq;
    __syncthreads();
    sq = red[0] + red[1] + red[2] + red[3];
    float scale = rsqrtf(sq * (1.f / DINNER) + EPSF);
    float4 w0 = *(const float4*)&rms_w[t * 8];
    float4 w1 = *(const float4*)&rms_w[t * 8 + 4];
    ushort8 o;
    o[0] = f2bf(g[0] * scale * w0.x);
    o[1] = f2bf(g[1] * scale * w0.y);
    o[2] = f2bf(g[2] * scale * w0.z);
    o[3] = f2bf(g[3] * scale * w0.w);
    o[4] = f2bf(g[4] * scale * w1.x);
    o[5] = f2bf(g[5] * scale * w1.y);
    o[6] = f2bf(g[6] * scale * w1.z);
    o[7] = f2bf(g[7] * scale * w1.w);
    *(ushort8*)&ynorm[(size_t)r * DINNER + t * 8] = o;
}

extern "C" void kernel_launch(void* const* d_in, const int* in_sizes, int n_in,
                              void* d_out, int out_size, void* d_ws, size_t ws_size,
                              hipStream_t stream) {
    (void)in_sizes; (void)n_in; (void)out_size; (void)ws_size;
    const float* x       = (const float*)d_in[0];
    const float* ln_w    = (const float*)d_in[1];
    const float* ln_b    = (const float*)d_in[2];
    const float* W_in    = (const float*)d_in[3];
    const float* conv_w  = (const float*)d_in[4];
    const float* conv_b  = (const float*)d_in[5];
    const float* dt_bias = (const float*)d_in[6];
    const float* A_log   = (const float*)d_in[7];
    const float* Dvec    = (const float*)d_in[8];
    const float* rms_w   = (const float*)d_in[9];
    const float* W_out   = (const float*)d_in[10];
    float* out = (float*)d_out;

    char* ws = (char*)d_ws;
    size_t off = 0;
    auto alloc = [&](size_t bytes) -> void* {
        void* p = ws + off;
        off += (bytes + 255) & ~(size_t)255;
        return p;
    };
    ushort_t* xn    = (ushort_t*)alloc((size_t)BL * DMODEL * 2);
    ushort_t* WinT  = (ushort_t*)alloc((size_t)NPAD * DMODEL * 2);
    ushort_t* zxb   = (ushort_t*)alloc((size_t)BL * NPAD * 2);
    ushort_t* xcv   = (ushort_t*)alloc((size_t)BL * DINNER * 2);
    ushort_t* Bcg   = (ushort_t*)alloc((size_t)BL * DSTATE * 2);
    ushort_t* Ccg   = (ushort_t*)alloc((size_t)BL * DSTATE * 2);
    float*    dtv   = (float*)   alloc((size_t)BL * NHEADS * 4);
    float*    dta   = (float*)   alloc((size_t)BL * NHEADS * 4);
    ushort_t* yv    = (ushort_t*)alloc((size_t)BL * DINNER * 2);
    ushort_t* ynorm = (ushort_t*)alloc((size_t)BL * DINNER * 2);
    ushort_t* WoutT = (ushort_t*)alloc((size_t)DMODEL * DINNER * 2);
    float*    wtr   = (float*)   alloc((size_t)4 * DXBC * 4);
    float*    cabuf = (float*)   alloc((size_t)BH * NCH * QCH * 4);
    float*    expcb = (float*)   alloc((size_t)BH * NCH * QCH * 4);
    float*    wbuf  = (float*)   alloc((size_t)BH * NCH * QCH * 4);
    float*    dtbuf = (float*)   alloc((size_t)BH * NCH * QCH * 4);
    float*    dtot  = (float*)   alloc((size_t)BH * NCH * 4);
    ushort_t* states= (ushort_t*)alloc((size_t)BH * NCH * 16384 * 2);

    ln_kernel<<<BL, 256, 0, stream>>>(x, ln_w, ln_b, xn);
    transpose_cast<<<dim3(NPAD / 32, DMODEL / 32), 256, 0, stream>>>(W_in, WinT, DMODEL, DPROJ);
    transpose_cast<<<dim3(DMODEL / 32, DINNER / 32), 256, 0, stream>>>(W_out, WoutT, DINNER, DMODEL);
    convw_tr<<<(DXBC + 255) / 256, 256, 0, stream>>>(conv_w, wtr);
    gemm256_bt<<<(NPAD / 256) * (BL / 256), 512, 0, stream>>>(xn, WinT, zxb, DMODEL, NPAD, NPAD / 256);
    conv_kernel<<<BL, 256, 0, stream>>>(zxb, wtr, conv_b, dt_bias, A_log, xcv, Bcg, Ccg, dtv, dta);
    cumsum_kernel<<<dim3(NCH, NHEADS, BATCH), 128, 0, stream>>>(dta, dtv, cabuf, expcb, wbuf, dtbuf, dtot);
    chunkstate_kernel<<<dim3(NCH, NHEADS, BATCH), 256, 0, stream>>>(xcv, Bcg, wbuf, states);
    statescan_kernel<<<dim3(16, BH), 256, 0, stream>>>(states, dtot);
    chunkout_kernel<<<dim3(NCH, NHEADS, BATCH), 256, 0, stream>>>(xcv, Bcg, Ccg, states, cabuf, expcb, dtbuf, Dvec, yv);
    gate_rms<<<BL, 256, 0, stream>>>(yv, zxb, rms_w, ynorm);
    gemm_bt<<<(DMODEL / 128) * (BL / 128), 256, 0, stream>>>(ynorm, WoutT, out, x, DINNER, DMODEL, DMODEL / 128);
}

// Round 12
// 202.841 us; speedup vs baseline: 1.0703x; 1.0703x over previous
//
#include <hip/hip_runtime.h>

typedef unsigned short ushort_t;
typedef __attribute__((ext_vector_type(8))) unsigned short ushort8;
typedef __attribute__((ext_vector_type(4))) unsigned short ushortv4;
typedef __attribute__((ext_vector_type(8))) __bf16 bf16x8;
typedef __attribute__((ext_vector_type(4))) float f32x4;

#define BATCH   2
#define SEQLEN  2048
#define BL      4096
#define DMODEL  1024
#define DINNER  2048
#define DSTATE  128
#define NHEADS  16
#define DXBC    2304
#define DPROJ   4368
#define NPAD    4480
#define EPSF    1e-5f
#define QCH     128
#define NCH     16          // SEQLEN / QCH
#define BH      32          // BATCH * NHEADS

// swizzled byte offset within a 256-byte LDS row (bf16, 128 cols)
#define SWZ(row, colbyte) ((colbyte) ^ (((row) & 7) << 4))

#define GLDS(gp, lp) __builtin_amdgcn_global_load_lds( \
    (const __attribute__((address_space(1))) void*)(gp), \
    (__attribute__((address_space(3))) void*)(lp), 16, 0, 0)

__device__ __forceinline__ float bf2f(ushort_t h) {
    unsigned int u = ((unsigned int)h) << 16;
    float f; __builtin_memcpy(&f, &u, 4); return f;
}
__device__ __forceinline__ ushort_t f2bf(float f) {
    unsigned int u; __builtin_memcpy(&u, &f, 4);
    unsigned int r = u + 0x7fffu + ((u >> 16) & 1u);
    return (ushort_t)(r >> 16);
}
__device__ __forceinline__ float siluf(float x) { return x / (1.f + expf(-x)); }
__device__ __forceinline__ float softplusf(float x) { return (x > 20.f) ? x : log1pf(expf(x)); }

// ---------------- LayerNorm + cast to bf16 ----------------
__global__ __launch_bounds__(256) void ln_kernel(const float* __restrict__ x,
        const float* __restrict__ w, const float* __restrict__ b, ushort_t* __restrict__ xn) {
    int r = blockIdx.x, t = threadIdx.x;
    const float* xr = x + (size_t)r * DMODEL;
    float4 v = *(const float4*)&xr[t * 4];
    float s  = v.x + v.y + v.z + v.w;
    float sq = v.x*v.x + v.y*v.y + v.z*v.z + v.w*v.w;
    __shared__ float red[8];
    #pragma unroll
    for (int m = 32; m >= 1; m >>= 1) { s += __shfl_xor(s, m, 64); sq += __shfl_xor(sq, m, 64); }
    int wv = t >> 6;
    if ((t & 63) == 0) { red[wv] = s; red[4 + wv] = sq; }
    __syncthreads();
    s  = red[0] + red[1] + red[2] + red[3];
    sq = red[4] + red[5] + red[6] + red[7];
    float mu  = s * (1.f / DMODEL);
    float var = sq * (1.f / DMODEL) - mu * mu;
    float inv = rsqrtf(var + EPSF);
    float4 wv4 = *(const float4*)&w[t * 4];
    float4 bv4 = *(const float4*)&b[t * 4];
    ushortv4 o;
    o[0] = f2bf((v.x - mu) * inv * wv4.x + bv4.x);
    o[1] = f2bf((v.y - mu) * inv * wv4.y + bv4.y);
    o[2] = f2bf((v.z - mu) * inv * wv4.z + bv4.z);
    o[3] = f2bf((v.w - mu) * inv * wv4.w + bv4.w);
    *(ushortv4*)&xn[(size_t)r * DMODEL + t * 4] = o;
}

// ---------------- merged weight prep: W_in^T, W_out^T (f32->bf16), conv_w^T ----------------
__device__ __forceinline__ void transpose_tile(const float* __restrict__ W,
        ushort_t* __restrict__ WT, int K, int N, int n0, int k0, int tid,
        float (*tile)[33]) {
    int tx = tid & 31, ty = tid >> 5;
    #pragma unroll
    for (int i = 0; i < 32; i += 8) {
        int n = n0 + tx;
        tile[ty + i][tx] = (n < N) ? W[(size_t)(k0 + ty + i) * N + n] : 0.f;
    }
    __syncthreads();
    #pragma unroll
    for (int i = 0; i < 32; i += 8) {
        WT[(size_t)(n0 + ty + i) * K + k0 + tx] = f2bf(tile[tx][ty + i]);
    }
}

#define NB_WIN  ((NPAD / 32) * (DMODEL / 32))     // 140*32 = 4480
#define NB_WOUT ((DMODEL / 32) * (DINNER / 32))   // 32*64  = 2048

__global__ __launch_bounds__(256) void prep_kernel(const float* __restrict__ W_in,
        const float* __restrict__ W_out, const float* __restrict__ conv_w,
        ushort_t* __restrict__ WinT, ushort_t* __restrict__ WoutT, float* __restrict__ wt) {
    __shared__ float tile[32][33];
    int bid = blockIdx.x, tid = threadIdx.x;
    if (bid < NB_WIN) {
        int n0 = (bid % (NPAD / 32)) * 32, k0 = (bid / (NPAD / 32)) * 32;
        transpose_tile(W_in, WinT, DMODEL, DPROJ, n0, k0, tid, tile);
    } else if (bid < NB_WIN + NB_WOUT) {
        int id = bid - NB_WIN;
        int n0 = (id % (DMODEL / 32)) * 32, k0 = (id / (DMODEL / 32)) * 32;
        transpose_tile(W_out, WoutT, DINNER, DMODEL, n0, k0, tid, tile);
    } else {
        int c = (bid - NB_WIN - NB_WOUT) * 256 + tid;
        if (c < DXBC) {
            float4 v = *(const float4*)&conv_w[c * 4];
            wt[0 * DXBC + c] = v.x;
            wt[1 * DXBC + c] = v.y;
            wt[2 * DXBC + c] = v.z;
            wt[3 * DXBC + c] = v.w;
        }
    }
}

// ---------------- GEMM: C = A[M][K](bf16) @ BT[N][K](bf16)^T (+resid) ----------------
// 3-buffer counted-vmcnt pipeline + k-chunk XOR swizzle (round-9/10 proven, 63.3 us).
template <bool OUTBF>
__global__ __launch_bounds__(256) void gemm_bt(const ushort_t* __restrict__ A,
        const ushort_t* __restrict__ BT, void* __restrict__ Cv,
        const float* __restrict__ resid, int K, int ldc, int nbx) {
    const int tid = threadIdx.x;
    const int nwg = gridDim.x;
    const int cpx = nwg >> 3;                    // blocks per XCD chunk
    const int lid = (blockIdx.x & 7) * cpx + (blockIdx.x >> 3);
    const int m0 = (lid / nbx) * 128, n0 = (lid % nbx) * 128;
    __shared__ ushort_t As[3][128 * 32];
    __shared__ ushort_t Bs[3][128 * 32];
    const int lane = tid & 63, wave = tid >> 6;
    const int wrow = wave * 32;
    const int srow = lane >> 2;
    const int selm = ((lane & 3) ^ (srow & 3)) * 8;
    const ushort_t* ag0 = A  + (size_t)(m0 + wrow + srow) * K + selm;
    const ushort_t* ag1 = ag0 + (size_t)16 * K;
    const ushort_t* bg0 = BT + (size_t)(n0 + wrow + srow) * K + selm;
    const ushort_t* bg1 = bg0 + (size_t)16 * K;
    const int wm = (wave >> 1) * 64, wn = (wave & 1) * 64;
    const int fr = lane & 15, ko = (lane >> 4) * 8;
    f32x4 acc[4][4];
    #pragma unroll
    for (int i = 0; i < 4; i++)
        #pragma unroll
        for (int j = 0; j < 4; j++) acc[i][j] = (f32x4){0.f, 0.f, 0.f, 0.f};
    const int nt = K >> 5;
    #pragma unroll
    for (int t = 0; t < 3; t++) {
        const size_t kof = (size_t)t * 32;
        GLDS(ag0 + kof, &As[t][wrow * 32]);
        GLDS(ag1 + kof, &As[t][(wrow + 16) * 32]);
        GLDS(bg0 + kof, &Bs[t][wrow * 32]);
        GLDS(bg1 + kof, &Bs[t][(wrow + 16) * 32]);
    }
    asm volatile("s_waitcnt vmcnt(8)" ::: "memory");
    __builtin_amdgcn_s_barrier();
    int cur = 0;
    for (int t = 0; t < nt; ++t) {
        if (t + 2 < nt) {
            int nb = cur + 2; if (nb >= 3) nb -= 3;
            const size_t kof = (size_t)(t + 2) * 32;
            GLDS(ag0 + kof, &As[nb][wrow * 32]);
            GLDS(ag1 + kof, &As[nb][(wrow + 16) * 32]);
            GLDS(bg0 + kof, &Bs[nb][wrow * 32]);
            GLDS(bg1 + kof, &Bs[nb][(wrow + 16) * 32]);
        }
        bf16x8 af[4], bfr[4];
        #pragma unroll
        for (int i = 0; i < 4; i++) {
            int row = wm + i * 16 + fr;
            af[i] = *(const bf16x8*)((const char*)&As[cur][0] + row * 64
                                     + ((ko * 2) ^ ((row & 3) << 4)));
        }
        #pragma unroll
        for (int j = 0; j < 4; j++) {
            int row = wn + j * 16 + fr;
            bfr[j] = *(const bf16x8*)((const char*)&Bs[cur][0] + row * 64
                                      + ((ko * 2) ^ ((row & 3) << 4)));
        }
        #pragma unroll
        for (int i = 0; i < 4; i++)
            #pragma unroll
            for (int j = 0; j < 4; j++)
                acc[i][j] = __builtin_amdgcn_mfma_f32_16x16x32_bf16(af[i], bfr[j], acc[i][j], 0, 0, 0);
        if (t + 2 < nt) asm volatile("s_waitcnt vmcnt(4)" ::: "memory");
        else            asm volatile("s_waitcnt vmcnt(0)" ::: "memory");
        __builtin_amdgcn_s_barrier();
        cur = (cur == 2) ? 0 : cur + 1;
    }
    const int r0 = (lane >> 4) * 4;
    #pragma unroll
    for (int i = 0; i < 4; i++)
        #pragma unroll
        for (int j = 0; j < 4; j++)
            #pragma unroll
            for (int r = 0; r < 4; r++) {
                int m = m0 + wm + i * 16 + r0 + r;
                int n = n0 + wn + j * 16 + fr;
                float v = acc[i][j][r];
                if (OUTBF) {
                    ((ushort_t*)Cv)[(size_t)m * ldc + n] = f2bf(v);
                } else {
                    if (resid) v += resid[(size_t)m * ldc + n];
                    ((float*)Cv)[(size_t)m * ldc + n] = v;
                }
            }
}

// ---------------- conv4 + SiLU + split + dt/dtA (bf16 zxb, transposed weights) ----------------
__global__ __launch_bounds__(256) void conv_kernel(const ushort_t* __restrict__ zxb,
        const float* __restrict__ wtr, const float* __restrict__ conv_b,
        const float* __restrict__ dt_bias, const float* __restrict__ A_log,
        ushort_t* __restrict__ xcv, ushort_t* __restrict__ Bcg, ushort_t* __restrict__ Ccg,
        float* __restrict__ dtv, float* __restrict__ dta) {
    int bid = blockIdx.x;
    int l = bid & (SEQLEN - 1);
    int tid = threadIdx.x;
    const ushort_t* rowp = zxb + (size_t)bid * NPAD;
    #pragma unroll 1
    for (int u = tid; u < DXBC / 8; u += 256) {
        int c0 = u * 8;
        float acc[8];
        {
            float4 b0 = *(const float4*)&conv_b[c0];
            float4 b1 = *(const float4*)&conv_b[c0 + 4];
            acc[0] = b0.x; acc[1] = b0.y; acc[2] = b0.z; acc[3] = b0.w;
            acc[4] = b1.x; acc[5] = b1.y; acc[6] = b1.z; acc[7] = b1.w;
        }
        #pragma unroll
        for (int k = 0; k < 4; k++) {
            int ll = l - 3 + k;
            if (ll >= 0) {
                ushort8 xv = *(const ushort8*)&rowp[(ptrdiff_t)(k - 3) * NPAD + DINNER + c0];
                float4 w0 = *(const float4*)&wtr[k * DXBC + c0];
                float4 w1 = *(const float4*)&wtr[k * DXBC + c0 + 4];
                acc[0] += bf2f((ushort_t)xv[0]) * w0.x;
                acc[1] += bf2f((ushort_t)xv[1]) * w0.y;
                acc[2] += bf2f((ushort_t)xv[2]) * w0.z;
                acc[3] += bf2f((ushort_t)xv[3]) * w0.w;
                acc[4] += bf2f((ushort_t)xv[4]) * w1.x;
                acc[5] += bf2f((ushort_t)xv[5]) * w1.y;
                acc[6] += bf2f((ushort_t)xv[6]) * w1.z;
                acc[7] += bf2f((ushort_t)xv[7]) * w1.w;
            }
        }
        ushort8 o;
        #pragma unroll
        for (int e = 0; e < 8; e++) o[e] = f2bf(siluf(acc[e]));
        if (c0 < DINNER)                *(ushort8*)&xcv[(size_t)bid * DINNER + c0] = o;
        else if (c0 < DINNER + DSTATE)  *(ushort8*)&Bcg[(size_t)bid * DSTATE + (c0 - DINNER)] = o;
        else                            *(ushort8*)&Ccg[(size_t)bid * DSTATE + (c0 - DINNER - DSTATE)] = o;
    }
    if (tid < NHEADS) {
        float raw = bf2f(rowp[DINNER + DXBC + tid]) + dt_bias[tid];
        float dt = softplusf(raw);
        float A = -expf(A_log[tid]);
        dtv[(size_t)bid * NHEADS + tid] = dt;
        dta[(size_t)bid * NHEADS + tid] = dt * A;
    }
}

// ---------------- chunk end-state + fused per-chunk cumsum ----------------
// First 128 threads compute the chunk's cumsum of dt*A, write cabuf/expca/dtbuf/dtot
// (for chunkout/statescan) and wsh (LDS, local use). Then the w-weighted
// X^T/B^T staging + MFMA as before.
__global__ __launch_bounds__(256) void chunkstate_kernel(const ushort_t* __restrict__ xcv,
        const ushort_t* __restrict__ Bcg, const float* __restrict__ dta,
        const float* __restrict__ dtv, float* __restrict__ cabuf, float* __restrict__ expca,
        float* __restrict__ dtbuf, float* __restrict__ dtot,
        ushort_t* __restrict__ states) {
    const int c = blockIdx.x, h = blockIdx.y, b = blockIdx.z;
    const int bh = b * NHEADS + h;
    const int tid = threadIdx.x;
    __shared__ ushort_t Xt[128 * 128];     // [p][j] swizzled
    __shared__ ushort_t Bt[128 * 128];     // [n][j] swizzled
    __shared__ float wsh[QCH];
    __shared__ float wsum[2];
    const size_t row0 = (size_t)b * SEQLEN + c * QCH;
    float pv = 0.f, dt = 0.f;
    if (tid < QCH) {
        const size_t row = row0 + tid;
        pv = dta[row * NHEADS + h];
        dt = dtv[row * NHEADS + h];
        #pragma unroll
        for (int off = 1; off < 64; off <<= 1) {
            float u = __shfl_up(pv, off, 64);
            if ((tid & 63) >= off) pv += u;
        }
        if ((tid & 63) == 63) wsum[tid >> 6] = pv;
    }
    __syncthreads();
    if (tid < QCH) {
        float tot = wsum[0] + wsum[1];
        if (tid >= 64) pv += wsum[0];
        const size_t idx = ((size_t)bh * NCH + c) * QCH + tid;
        cabuf[idx] = pv;
        expca[idx] = expf(pv);
        dtbuf[idx] = dt;
        wsh[tid]   = expf(tot - pv) * dt;
        if (tid == 0) dtot[bh * NCH + c] = expf(tot);
    }
    __syncthreads();
    {
        const int f = tid & 127;
        const int jh = (tid >> 7) * 64;
        const ushort_t* xsrc = xcv + (row0 + jh) * DINNER + h * 128 + f;
        const ushort_t* bsrc = Bcg + (row0 + jh) * DSTATE + f;
        char* xrow = (char*)Xt + f * 256;
        char* brow = (char*)Bt + f * 256;
        #pragma unroll 2
        for (int e8 = 0; e8 < 8; e8++) {
            ushort8 tx, tb;
            #pragma unroll
            for (int e = 0; e < 8; e++) {
                int j = e8 * 8 + e;
                tx[e] = xsrc[(size_t)j * DINNER];
                tb[e] = f2bf(bf2f(bsrc[(size_t)j * DSTATE]) * wsh[jh + j]);
            }
            int cb = (jh + e8 * 8) * 2;
            *(ushort8*)(xrow + SWZ(f, cb)) = tx;
            *(ushort8*)(brow + SWZ(f, cb)) = tb;
        }
    }
    __syncthreads();
    const int lane = tid & 63, wave = tid >> 6;
    const int wp = (wave >> 1) * 64, wn = (wave & 1) * 64;
    const int fr = lane & 15, ko = (lane >> 4) * 8;
    f32x4 acc[4][4];
    #pragma unroll
    for (int i = 0; i < 4; i++)
        #pragma unroll
        for (int j = 0; j < 4; j++) acc[i][j] = (f32x4){0.f, 0.f, 0.f, 0.f};
    for (int k0 = 0; k0 < 128; k0 += 32) {
        bf16x8 af[4], bfr[4];
        #pragma unroll
        for (int i = 0; i < 4; i++) {
            int rp = wp + i * 16 + fr;
            af[i] = *(const bf16x8*)((const char*)Xt + rp * 256 + SWZ(rp, (k0 + ko) * 2));
        }
        #pragma unroll
        for (int j = 0; j < 4; j++) {
            int rn = wn + j * 16 + fr;
            bfr[j] = *(const bf16x8*)((const char*)Bt + rn * 256 + SWZ(rn, (k0 + ko) * 2));
        }
        #pragma unroll
        for (int i = 0; i < 4; i++)
            #pragma unroll
            for (int j = 0; j < 4; j++)
                acc[i][j] = __builtin_amdgcn_mfma_f32_16x16x32_bf16(af[i], bfr[j], acc[i][j], 0, 0, 0);
    }
    const int r0 = (lane >> 4) * 4;
    ushort_t* outp = states + ((size_t)bh * NCH + c) * 16384;
    #pragma unroll
    for (int i = 0; i < 4; i++)
        #pragma unroll
        for (int j = 0; j < 4; j++)
            #pragma unroll
            for (int r = 0; r < 4; r++)
                outp[(wp + i * 16 + r0 + r) * 128 + wn + j * 16 + fr] = f2bf(acc[i][j][r]);
}

// ---------------- inter-chunk state scan (in place, bf16 storage, f32 accum) ----------------
__global__ __launch_bounds__(256) void statescan_kernel(ushort_t* __restrict__ states,
        const float* __restrict__ dtot) {
    const int pseg = blockIdx.x, bh = blockIdx.y;
    const int tid = threadIdx.x;
    const int p = pseg * 8 + (tid >> 5);
    const int n4 = (tid & 31) * 4;
    ushort_t* base = states + (size_t)bh * NCH * 16384 + p * 128 + n4;
    const float* dtp = dtot + bh * NCH;
    float r0 = 0.f, r1 = 0.f, r2 = 0.f, r3 = 0.f;
    #pragma unroll 1
    for (int c = 0; c < NCH; c++) {
        ushortv4* ptr = (ushortv4*)(base + (size_t)c * 16384);
        ushortv4 cs = *ptr;
        ushortv4 o;
        o[0] = f2bf(r0); o[1] = f2bf(r1); o[2] = f2bf(r2); o[3] = f2bf(r3);
        *ptr = o;
        float d = dtp[c];
        r0 = r0 * d + bf2f(cs[0]);
        r1 = r1 * d + bf2f(cs[1]);
        r2 = r2 * d + bf2f(cs[2]);
        r3 = r3 * d + bf2f(cs[3]);
    }
}

// ---------------- chunk output: y = exp(ca)*(C @ S_init) + (mask(CB^T) masked-decay) @ X ----------------
__global__ __launch_bounds__(256) void chunkout_kernel(const ushort_t* __restrict__ xcv,
        const ushort_t* __restrict__ Bcg, const ushort_t* __restrict__ Ccg,
        const ushort_t* __restrict__ states, const float* __restrict__ cabuf,
        const float* __restrict__ expca, const float* __restrict__ dtbuf,
        const float* __restrict__ Dvec, ushort_t* __restrict__ yv) {
    const int c = blockIdx.x, h = blockIdx.y, b = blockIdx.z;
    const int bh = b * NHEADS + h;
    const int tid = threadIdx.x;
    __shared__ ushort_t R1[128 * 128];   // ST -> B -> P
    __shared__ ushort_t R2[128 * 128];   // C -> Xt
    __shared__ float cash[QCH], dtsh[QCH], exsh[QCH];
    const size_t aidx = ((size_t)bh * NCH + c) * QCH;
    if (tid < QCH) {
        cash[tid] = cabuf[aidx + tid];
        dtsh[tid] = dtbuf[aidx + tid];
        exsh[tid] = expca[aidx + tid];
    }
    const size_t row0 = (size_t)b * SEQLEN + c * QCH;
    {
        const ushort_t* sp = states + ((size_t)bh * NCH + c) * 16384;
        #pragma unroll
        for (int it = 0; it < 8; it++) {
            int g = tid + it * 256;
            int r = g >> 4, n8 = (g & 15) * 8;
            ushort8 vc = *(const ushort8*)&Ccg[(row0 + r) * DSTATE + n8];
            ushort8 vs = *(const ushort8*)&sp[r * 128 + n8];
            int cb = n8 * 2;
            *(ushort8*)((char*)R2 + r * 256 + SWZ(r, cb)) = vc;
            *(ushort8*)((char*)R1 + r * 256 + SWZ(r, cb)) = vs;
        }
    }
    __syncthreads();
    const int lane = tid & 63, wave = tid >> 6;
    const int fr = lane & 15, ko = (lane >> 4) * 8, r0 = (lane >> 4) * 4;
    const int wty = (wave >> 1) * 64, wpy = (wave & 1) * 64;
    f32x4 y_[4][4];
    #pragma unroll
    for (int i = 0; i < 4; i++)
        #pragma unroll
        for (int j = 0; j < 4; j++) y_[i][j] = (f32x4){0.f, 0.f, 0.f, 0.f};
    for (int k0 = 0; k0 < 128; k0 += 32) {
        bf16x8 af[4], bfr[4];
        #pragma unroll
        for (int i = 0; i < 4; i++) {
            int rt = wty + i * 16 + fr;
            af[i] = *(const bf16x8*)((const char*)R2 + rt * 256 + SWZ(rt, (k0 + ko) * 2));
        }
        #pragma unroll
        for (int j = 0; j < 4; j++) {
            int rp = wpy + j * 16 + fr;
            bfr[j] = *(const bf16x8*)((const char*)R1 + rp * 256 + SWZ(rp, (k0 + ko) * 2));
        }
        #pragma unroll
        for (int i = 0; i < 4; i++)
            #pragma unroll
            for (int j = 0; j < 4; j++)
                y_[i][j] = __builtin_amdgcn_mfma_f32_16x16x32_bf16(af[i], bfr[j], y_[i][j], 0, 0, 0);
    }
    #pragma unroll
    for (int i = 0; i < 4; i++)
        #pragma unroll
        for (int r = 0; r < 4; r++) {
            float sc = exsh[wty + i * 16 + r0 + r];
            #pragma unroll
            for (int j = 0; j < 4; j++) y_[i][j][r] *= sc;
        }
    __syncthreads();
    #pragma unroll
    for (int it = 0; it < 8; it++) {
        int g = tid + it * 256;
        int r = g >> 4, n8 = (g & 15) * 8;
        ushort8 vb = *(const ushort8*)&Bcg[(row0 + r) * DSTATE + n8];
        *(ushort8*)((char*)R1 + r * 256 + SWZ(r, n8 * 2)) = vb;
    }
    __syncthreads();
    const int wj = (wave >> 1) * 64, wt = (wave & 1) * 64;
    f32x4 g_[4][4];
    #pragma unroll
    for (int i = 0; i < 4; i++)
        #pragma unroll
        for (int t = 0; t < 4; t++) g_[i][t] = (f32x4){0.f, 0.f, 0.f, 0.f};
    if (!(wj == 64 && wt == 0)) {
        for (int k0 = 0; k0 < 128; k0 += 32) {
            bf16x8 af[4], bfr[4];
            #pragma unroll
            for (int i = 0; i < 4; i++) {
                int rj = wj + i * 16 + fr;
                af[i] = *(const bf16x8*)((const char*)R1 + rj * 256 + SWZ(rj, (k0 + ko) * 2));
            }
            #pragma unroll
            for (int t = 0; t < 4; t++) {
                int rt = wt + t * 16 + fr;
                bfr[t] = *(const bf16x8*)((const char*)R2 + rt * 256 + SWZ(rt, (k0 + ko) * 2));
            }
            #pragma unroll
            for (int i = 0; i < 4; i++)
                #pragma unroll
                for (int t = 0; t < 4; t++)
                    g_[i][t] = __builtin_amdgcn_mfma_f32_16x16x32_bf16(af[i], bfr[t], g_[i][t], 0, 0, 0);
        }
    }
    __syncthreads();
    {
        const float Dh = Dvec[h];
        #pragma unroll
        for (int i = 0; i < 4; i++) {
            #pragma unroll
            for (int t = 0; t < 4; t++) {
                int tt = wt + t * 16 + fr;
                int jj0 = wj + i * 16 + r0;
                ushortv4 pk;
                #pragma unroll
                for (int r = 0; r < 4; r++) {
                    int jj = jj0 + r;
                    float val = 0.f;
                    if (jj <= tt) {
                        val = g_[i][t][r] * expf(cash[tt] - cash[jj]) * dtsh[jj];
                        if (jj == tt) val += Dh;
                    }
                    pk[r] = f2bf(val);
                }
                *(ushortv4*)((char*)R1 + tt * 256 + SWZ(tt, jj0 * 2)) = pk;
            }
        }
        const int f = tid & 127;
        const int jh = (tid >> 7) * 64;
        const ushort_t* xsrc = xcv + (row0 + jh) * DINNER + h * 128 + f;
        char* xrow = (char*)R2 + f * 256;
        #pragma unroll 2
        for (int e8 = 0; e8 < 8; e8++) {
            ushort8 tx;
            #pragma unroll
            for (int e = 0; e < 8; e++) tx[e] = xsrc[(size_t)(e8 * 8 + e) * DINNER];
            int cb = (jh + e8 * 8) * 2;
            *(ushort8*)(xrow + SWZ(f, cb)) = tx;
        }
    }
    __syncthreads();
    const int kmax = wty + 64;
    for (int k0 = 0; k0 < kmax; k0 += 32) {
        bf16x8 af[4], bfr[4];
        #pragma unroll
        for (int i = 0; i < 4; i++) {
            int rt = wty + i * 16 + fr;
            af[i] = *(const bf16x8*)((const char*)R1 + rt * 256 + SWZ(rt, (k0 + ko) * 2));
        }
        #pragma unroll
        for (int j = 0; j < 4; j++) {
            int rp = wpy + j * 16 + fr;
            bfr[j] = *(const bf16x8*)((const char*)R2 + rp * 256 + SWZ(rp, (k0 + ko) * 2));
        }
        #pragma unroll
        for (int i = 0; i < 4; i++)
            #pragma unroll
            for (int j = 0; j < 4; j++)
                y_[i][j] = __builtin_amdgcn_mfma_f32_16x16x32_bf16(af[i], bfr[j], y_[i][j], 0, 0, 0);
    }
    #pragma unroll
    for (int i = 0; i < 4; i++)
        #pragma unroll
        for (int j = 0; j < 4; j++)
            #pragma unroll
            for (int r = 0; r < 4; r++) {
                int t = wty + i * 16 + r0 + r;
                int p = wpy + j * 16 + fr;
                yv[(row0 + t) * DINNER + h * 128 + p] = f2bf(y_[i][j][r]);
            }
}

// ---------------- gate (y * silu(z)) + RMSNorm -> bf16 (z from bf16 zxb) ----------------
__global__ __launch_bounds__(256) void gate_rms(const ushort_t* __restrict__ yv,
        const ushort_t* __restrict__ zxb, const float* __restrict__ rms_w,
        ushort_t* __restrict__ ynorm) {
    int r = blockIdx.x, t = threadIdx.x;
    const ushort_t* yr = yv + (size_t)r * DINNER;
    const ushort_t* zr = zxb + (size_t)r * NPAD;
    ushort8 y8 = *(const ushort8*)&yr[t * 8];
    ushort8 z8 = *(const ushort8*)&zr[t * 8];
    float g[8];
    #pragma unroll
    for (int j = 0; j < 8; j++)
        g[j] = bf2f((ushort_t)y8[j]) * siluf(bf2f((ushort_t)z8[j]));
    float sq = 0.f;
    #pragma unroll
    for (int j = 0; j < 8; j++) sq += g[j] * g[j];
    __shared__ float red[4];
    #pragma unroll
    for (int m = 32; m >= 1; m >>= 1) sq += __shfl_xor(sq, m, 64);
    int wv = t >> 6;
    if ((t & 63) == 0) red[wv] = sq;
    __syncthreads();
    sq = red[0] + red[1] + red[2] + red[3];
    float scale = rsqrtf(sq * (1.f / DINNER) + EPSF);
    float4 w0 = *(const float4*)&rms_w[t * 8];
    float4 w1 = *(const float4*)&rms_w[t * 8 + 4];
    ushort8 o;
    o[0] = f2bf(g[0] * scale * w0.x);
    o[1] = f2bf(g[1] * scale * w0.y);
    o[2] = f2bf(g[2] * scale * w0.z);
    o[3] = f2bf(g[3] * scale * w0.w);
    o[4] = f2bf(g[4] * scale * w1.x);
    o[5] = f2bf(g[5] * scale * w1.y);
    o[6] = f2bf(g[6] * scale * w1.z);
    o[7] = f2bf(g[7] * scale * w1.w);
    *(ushort8*)&ynorm[(size_t)r * DINNER + t * 8] = o;
}

extern "C" void kernel_launch(void* const* d_in, const int* in_sizes, int n_in,
                              void* d_out, int out_size, void* d_ws, size_t ws_size,
                              hipStream_t stream) {
    (void)in_sizes; (void)n_in; (void)out_size; (void)ws_size;
    const float* x       = (const float*)d_in[0];
    const float* ln_w    = (const float*)d_in[1];
    const float* ln_b    = (const float*)d_in[2];
    const float* W_in    = (const float*)d_in[3];
    const float* conv_w  = (const float*)d_in[4];
    const float* conv_b  = (const float*)d_in[5];
    const float* dt_bias = (const float*)d_in[6];
    const float* A_log   = (const float*)d_in[7];
    const float* Dvec    = (const float*)d_in[8];
    const float* rms_w   = (const float*)d_in[9];
    const float* W_out   = (const float*)d_in[10];
    float* out = (float*)d_out;

    char* ws = (char*)d_ws;
    size_t off = 0;
    auto alloc = [&](size_t bytes) -> void* {
        void* p = ws + off;
        off += (bytes + 255) & ~(size_t)255;
        return p;
    };
    ushort_t* xn    = (ushort_t*)alloc((size_t)BL * DMODEL * 2);
    ushort_t* WinT  = (ushort_t*)alloc((size_t)NPAD * DMODEL * 2);
    ushort_t* zxb   = (ushort_t*)alloc((size_t)BL * NPAD * 2);
    ushort_t* xcv   = (ushort_t*)alloc((size_t)BL * DINNER * 2);
    ushort_t* Bcg   = (ushort_t*)alloc((size_t)BL * DSTATE * 2);
    ushort_t* Ccg   = (ushort_t*)alloc((size_t)BL * DSTATE * 2);
    float*    dtv   = (float*)   alloc((size_t)BL * NHEADS * 4);
    float*    dta   = (float*)   alloc((size_t)BL * NHEADS * 4);
    ushort_t* yv    = (ushort_t*)alloc((size_t)BL * DINNER * 2);
    ushort_t* ynorm = (ushort_t*)alloc((size_t)BL * DINNER * 2);
    ushort_t* WoutT = (ushort_t*)alloc((size_t)DMODEL * DINNER * 2);
    float*    wtr   = (float*)   alloc((size_t)4 * DXBC * 4);
    float*    cabuf = (float*)   alloc((size_t)BH * NCH * QCH * 4);
    float*    expcb = (float*)   alloc((size_t)BH * NCH * QCH * 4);
    float*    dtbuf = (float*)   alloc((size_t)BH * NCH * QCH * 4);
    float*    dtot  = (float*)   alloc((size_t)BH * NCH * 4);
    ushort_t* states= (ushort_t*)alloc((size_t)BH * NCH * 16384 * 2);

    ln_kernel<<<BL, 256, 0, stream>>>(x, ln_w, ln_b, xn);
    prep_kernel<<<NB_WIN + NB_WOUT + (DXBC + 255) / 256, 256, 0, stream>>>(
        W_in, W_out, conv_w, WinT, WoutT, wtr);
    gemm_bt<true><<<(NPAD / 128) * (BL / 128), 256, 0, stream>>>(xn, WinT, zxb, nullptr, DMODEL, NPAD, NPAD / 128);
    conv_kernel<<<BL, 256, 0, stream>>>(zxb, wtr, conv_b, dt_bias, A_log, xcv, Bcg, Ccg, dtv, dta);
    chunkstate_kernel<<<dim3(NCH, NHEADS, BATCH), 256, 0, stream>>>(
        xcv, Bcg, dta, dtv, cabuf, expcb, dtbuf, dtot, states);
    statescan_kernel<<<dim3(16, BH), 256, 0, stream>>>(states, dtot);
    chunkout_kernel<<<dim3(NCH, NHEADS, BATCH), 256, 0, stream>>>(xcv, Bcg, Ccg, states, cabuf, expcb, dtbuf, Dvec, yv);
    gate_rms<<<BL, 256, 0, stream>>>(yv, zxb, rms_w, ynorm);
    gemm_bt<false><<<(DMODEL / 128) * (BL / 128), 256, 0, stream>>>(ynorm, WoutT, out, x, DINNER, DMODEL, DMODEL / 128);
}

// Round 13
// 200.629 us; speedup vs baseline: 1.0821x; 1.0110x over previous
//
#include <hip/hip_runtime.h>

typedef unsigned short ushort_t;
typedef __attribute__((ext_vector_type(8))) unsigned short ushort8;
typedef __attribute__((ext_vector_type(4))) unsigned short ushortv4;
typedef __attribute__((ext_vector_type(8))) __bf16 bf16x8;
typedef __attribute__((ext_vector_type(4))) float f32x4;

#define BATCH   2
#define SEQLEN  2048
#define BL      4096
#define DMODEL  1024
#define DINNER  2048
#define DSTATE  128
#define NHEADS  16
#define DXBC    2304
#define DPROJ   4368
#define NPAD    4480
#define EPSF    1e-5f
#define QCH     128
#define NCH     16          // SEQLEN / QCH
#define BH      32          // BATCH * NHEADS

// swizzled byte offset within a 256-byte LDS row (bf16, 128 cols)
#define SWZ(row, colbyte) ((colbyte) ^ (((row) & 7) << 4))

#define GLDS(gp, lp) __builtin_amdgcn_global_load_lds( \
    (const __attribute__((address_space(1))) void*)(gp), \
    (__attribute__((address_space(3))) void*)(lp), 16, 0, 0)

__device__ __forceinline__ float bf2f(ushort_t h) {
    unsigned int u = ((unsigned int)h) << 16;
    float f; __builtin_memcpy(&f, &u, 4); return f;
}
__device__ __forceinline__ ushort_t f2bf(float f) {
    unsigned int u; __builtin_memcpy(&u, &f, 4);
    unsigned int r = u + 0x7fffu + ((u >> 16) & 1u);
    return (ushort_t)(r >> 16);
}
__device__ __forceinline__ float siluf(float x) { return x / (1.f + expf(-x)); }
__device__ __forceinline__ float softplusf(float x) { return (x > 20.f) ? x : log1pf(expf(x)); }

// ---------------- LayerNorm + cast to bf16 ----------------
__global__ __launch_bounds__(256) void ln_kernel(const float* __restrict__ x,
        const float* __restrict__ w, const float* __restrict__ b, ushort_t* __restrict__ xn) {
    int r = blockIdx.x, t = threadIdx.x;
    const float* xr = x + (size_t)r * DMODEL;
    float4 v = *(const float4*)&xr[t * 4];
    float s  = v.x + v.y + v.z + v.w;
    float sq = v.x*v.x + v.y*v.y + v.z*v.z + v.w*v.w;
    __shared__ float red[8];
    #pragma unroll
    for (int m = 32; m >= 1; m >>= 1) { s += __shfl_xor(s, m, 64); sq += __shfl_xor(sq, m, 64); }
    int wv = t >> 6;
    if ((t & 63) == 0) { red[wv] = s; red[4 + wv] = sq; }
    __syncthreads();
    s  = red[0] + red[1] + red[2] + red[3];
    sq = red[4] + red[5] + red[6] + red[7];
    float mu  = s * (1.f / DMODEL);
    float var = sq * (1.f / DMODEL) - mu * mu;
    float inv = rsqrtf(var + EPSF);
    float4 wv4 = *(const float4*)&w[t * 4];
    float4 bv4 = *(const float4*)&b[t * 4];
    ushortv4 o;
    o[0] = f2bf((v.x - mu) * inv * wv4.x + bv4.x);
    o[1] = f2bf((v.y - mu) * inv * wv4.y + bv4.y);
    o[2] = f2bf((v.z - mu) * inv * wv4.z + bv4.z);
    o[3] = f2bf((v.w - mu) * inv * wv4.w + bv4.w);
    *(ushortv4*)&xn[(size_t)r * DMODEL + t * 4] = o;
}

// ---------------- merged weight prep: W_in^T, W_out^T (f32->bf16), conv_w^T ----------------
__device__ __forceinline__ void transpose_tile(const float* __restrict__ W,
        ushort_t* __restrict__ WT, int K, int N, int n0, int k0, int tid,
        float (*tile)[33]) {
    int tx = tid & 31, ty = tid >> 5;
    #pragma unroll
    for (int i = 0; i < 32; i += 8) {
        int n = n0 + tx;
        tile[ty + i][tx] = (n < N) ? W[(size_t)(k0 + ty + i) * N + n] : 0.f;
    }
    __syncthreads();
    #pragma unroll
    for (int i = 0; i < 32; i += 8) {
        WT[(size_t)(n0 + ty + i) * K + k0 + tx] = f2bf(tile[tx][ty + i]);
    }
}

#define NB_WIN  ((NPAD / 32) * (DMODEL / 32))     // 140*32 = 4480
#define NB_WOUT ((DMODEL / 32) * (DINNER / 32))   // 32*64  = 2048

__global__ __launch_bounds__(256) void prep_kernel(const float* __restrict__ W_in,
        const float* __restrict__ W_out, const float* __restrict__ conv_w,
        ushort_t* __restrict__ WinT, ushort_t* __restrict__ WoutT, float* __restrict__ wt) {
    __shared__ float tile[32][33];
    int bid = blockIdx.x, tid = threadIdx.x;
    if (bid < NB_WIN) {
        int n0 = (bid % (NPAD / 32)) * 32, k0 = (bid / (NPAD / 32)) * 32;
        transpose_tile(W_in, WinT, DMODEL, DPROJ, n0, k0, tid, tile);
    } else if (bid < NB_WIN + NB_WOUT) {
        int id = bid - NB_WIN;
        int n0 = (id % (DMODEL / 32)) * 32, k0 = (id / (DMODEL / 32)) * 32;
        transpose_tile(W_out, WoutT, DINNER, DMODEL, n0, k0, tid, tile);
    } else {
        int c = (bid - NB_WIN - NB_WOUT) * 256 + tid;
        if (c < DXBC) {
            float4 v = *(const float4*)&conv_w[c * 4];
            wt[0 * DXBC + c] = v.x;
            wt[1 * DXBC + c] = v.y;
            wt[2 * DXBC + c] = v.z;
            wt[3 * DXBC + c] = v.w;
        }
    }
}

// ---------------- GEMM: C = A[M][K](bf16) @ BT[N][K](bf16)^T (+resid) ----------------
// 3-buffer counted-vmcnt pipeline + k-chunk XOR swizzle (round-9/10 proven, 63.3 us).
template <bool OUTBF>
__global__ __launch_bounds__(256) void gemm_bt(const ushort_t* __restrict__ A,
        const ushort_t* __restrict__ BT, void* __restrict__ Cv,
        const float* __restrict__ resid, int K, int ldc, int nbx) {
    const int tid = threadIdx.x;
    const int nwg = gridDim.x;
    const int cpx = nwg >> 3;                    // blocks per XCD chunk
    const int lid = (blockIdx.x & 7) * cpx + (blockIdx.x >> 3);
    const int m0 = (lid / nbx) * 128, n0 = (lid % nbx) * 128;
    __shared__ ushort_t As[3][128 * 32];
    __shared__ ushort_t Bs[3][128 * 32];
    const int lane = tid & 63, wave = tid >> 6;
    const int wrow = wave * 32;
    const int srow = lane >> 2;
    const int selm = ((lane & 3) ^ (srow & 3)) * 8;
    const ushort_t* ag0 = A  + (size_t)(m0 + wrow + srow) * K + selm;
    const ushort_t* ag1 = ag0 + (size_t)16 * K;
    const ushort_t* bg0 = BT + (size_t)(n0 + wrow + srow) * K + selm;
    const ushort_t* bg1 = bg0 + (size_t)16 * K;
    const int wm = (wave >> 1) * 64, wn = (wave & 1) * 64;
    const int fr = lane & 15, ko = (lane >> 4) * 8;
    f32x4 acc[4][4];
    #pragma unroll
    for (int i = 0; i < 4; i++)
        #pragma unroll
        for (int j = 0; j < 4; j++) acc[i][j] = (f32x4){0.f, 0.f, 0.f, 0.f};
    const int nt = K >> 5;
    #pragma unroll
    for (int t = 0; t < 3; t++) {
        const size_t kof = (size_t)t * 32;
        GLDS(ag0 + kof, &As[t][wrow * 32]);
        GLDS(ag1 + kof, &As[t][(wrow + 16) * 32]);
        GLDS(bg0 + kof, &Bs[t][wrow * 32]);
        GLDS(bg1 + kof, &Bs[t][(wrow + 16) * 32]);
    }
    asm volatile("s_waitcnt vmcnt(8)" ::: "memory");
    __builtin_amdgcn_s_barrier();
    int cur = 0;
    for (int t = 0; t < nt; ++t) {
        if (t + 2 < nt) {
            int nb = cur + 2; if (nb >= 3) nb -= 3;
            const size_t kof = (size_t)(t + 2) * 32;
            GLDS(ag0 + kof, &As[nb][wrow * 32]);
            GLDS(ag1 + kof, &As[nb][(wrow + 16) * 32]);
            GLDS(bg0 + kof, &Bs[nb][wrow * 32]);
            GLDS(bg1 + kof, &Bs[nb][(wrow + 16) * 32]);
        }
        bf16x8 af[4], bfr[4];
        #pragma unroll
        for (int i = 0; i < 4; i++) {
            int row = wm + i * 16 + fr;
            af[i] = *(const bf16x8*)((const char*)&As[cur][0] + row * 64
                                     + ((ko * 2) ^ ((row & 3) << 4)));
        }
        #pragma unroll
        for (int j = 0; j < 4; j++) {
            int row = wn + j * 16 + fr;
            bfr[j] = *(const bf16x8*)((const char*)&Bs[cur][0] + row * 64
                                      + ((ko * 2) ^ ((row & 3) << 4)));
        }
        #pragma unroll
        for (int i = 0; i < 4; i++)
            #pragma unroll
            for (int j = 0; j < 4; j++)
                acc[i][j] = __builtin_amdgcn_mfma_f32_16x16x32_bf16(af[i], bfr[j], acc[i][j], 0, 0, 0);
        if (t + 2 < nt) asm volatile("s_waitcnt vmcnt(4)" ::: "memory");
        else            asm volatile("s_waitcnt vmcnt(0)" ::: "memory");
        __builtin_amdgcn_s_barrier();
        cur = (cur == 2) ? 0 : cur + 1;
    }
    const int r0 = (lane >> 4) * 4;
    #pragma unroll
    for (int i = 0; i < 4; i++)
        #pragma unroll
        for (int j = 0; j < 4; j++)
            #pragma unroll
            for (int r = 0; r < 4; r++) {
                int m = m0 + wm + i * 16 + r0 + r;
                int n = n0 + wn + j * 16 + fr;
                float v = acc[i][j][r];
                if (OUTBF) {
                    ((ushort_t*)Cv)[(size_t)m * ldc + n] = f2bf(v);
                } else {
                    if (resid) v += resid[(size_t)m * ldc + n];
                    ((float*)Cv)[(size_t)m * ldc + n] = v;
                }
            }
}

// ---------------- conv4 + SiLU + split + dt/dtA — 8 timesteps per block ----------------
// grid BL/8 = 512 blocks. Thread loads 11 rows of its 8-channel column once,
// computes 8 outputs (read amplification 4x -> 1.375x; 8 independent acc chains).
__global__ __launch_bounds__(256) void conv_kernel(const ushort_t* __restrict__ zxb,
        const float* __restrict__ wtr, const float* __restrict__ conv_b,
        const float* __restrict__ dt_bias, const float* __restrict__ A_log,
        ushort_t* __restrict__ xcv, ushort_t* __restrict__ Bcg, ushort_t* __restrict__ Ccg,
        float* __restrict__ dtv, float* __restrict__ dta) {
    const int bid = blockIdx.x;
    const int lpb = SEQLEN / 8;
    const int b = bid / lpb, lt = bid % lpb;
    const int l0 = lt * 8;
    const size_t row0 = (size_t)b * SEQLEN + l0;
    const ushort_t* base = zxb + row0 * NPAD + DINNER;   // xBC col base at t=0
    const int tid = threadIdx.x;
    #pragma unroll 1
    for (int u = tid; u < DXBC / 8; u += 256) {
        const int c0 = u * 8;
        ushort8 xr[11];
        #pragma unroll
        for (int r = 0; r < 11; r++) {
            int ll = l0 - 3 + r;
            if (ll >= 0) xr[r] = *(const ushort8*)&base[(ptrdiff_t)(r - 3) * NPAD + c0];
            else         xr[r] = (ushort8){0,0,0,0,0,0,0,0};
        }
        float w[4][8];
        #pragma unroll
        for (int k = 0; k < 4; k++) {
            float4 w0 = *(const float4*)&wtr[k * DXBC + c0];
            float4 w1 = *(const float4*)&wtr[k * DXBC + c0 + 4];
            w[k][0] = w0.x; w[k][1] = w0.y; w[k][2] = w0.z; w[k][3] = w0.w;
            w[k][4] = w1.x; w[k][5] = w1.y; w[k][6] = w1.z; w[k][7] = w1.w;
        }
        float bias[8];
        {
            float4 b0 = *(const float4*)&conv_b[c0];
            float4 b1 = *(const float4*)&conv_b[c0 + 4];
            bias[0] = b0.x; bias[1] = b0.y; bias[2] = b0.z; bias[3] = b0.w;
            bias[4] = b1.x; bias[5] = b1.y; bias[6] = b1.z; bias[7] = b1.w;
        }
        #pragma unroll
        for (int t = 0; t < 8; t++) {
            float acc[8];
            #pragma unroll
            for (int e = 0; e < 8; e++) acc[e] = bias[e];
            #pragma unroll
            for (int k = 0; k < 4; k++)
                #pragma unroll
                for (int e = 0; e < 8; e++)
                    acc[e] += bf2f((ushort_t)xr[t + k][e]) * w[k][e];
            ushort8 o;
            #pragma unroll
            for (int e = 0; e < 8; e++) o[e] = f2bf(siluf(acc[e]));
            const size_t rw = row0 + t;
            if (c0 < DINNER)                *(ushort8*)&xcv[rw * DINNER + c0] = o;
            else if (c0 < DINNER + DSTATE)  *(ushort8*)&Bcg[rw * DSTATE + (c0 - DINNER)] = o;
            else                            *(ushort8*)&Ccg[rw * DSTATE + (c0 - DINNER - DSTATE)] = o;
        }
    }
    if (tid < 128) {
        const int t = tid >> 4, h = tid & 15;
        const size_t rw = row0 + t;
        float raw = bf2f(zxb[rw * NPAD + DINNER + DXBC + h]) + dt_bias[h];
        float dt = softplusf(raw);
        float A = -expf(A_log[h]);
        dtv[rw * NHEADS + h] = dt;
        dta[rw * NHEADS + h] = dt * A;
    }
}

// ---------------- chunk end-state + fused per-chunk cumsum ----------------
__global__ __launch_bounds__(256) void chunkstate_kernel(const ushort_t* __restrict__ xcv,
        const ushort_t* __restrict__ Bcg, const float* __restrict__ dta,
        const float* __restrict__ dtv, float* __restrict__ cabuf, float* __restrict__ expca,
        float* __restrict__ dtbuf, float* __restrict__ dtot,
        ushort_t* __restrict__ states) {
    const int c = blockIdx.x, h = blockIdx.y, b = blockIdx.z;
    const int bh = b * NHEADS + h;
    const int tid = threadIdx.x;
    __shared__ ushort_t Xt[128 * 128];     // [p][j] swizzled
    __shared__ ushort_t Bt[128 * 128];     // [n][j] swizzled
    __shared__ float wsh[QCH];
    __shared__ float wsum[2];
    const size_t row0 = (size_t)b * SEQLEN + c * QCH;
    float pv = 0.f, dt = 0.f;
    if (tid < QCH) {
        const size_t row = row0 + tid;
        pv = dta[row * NHEADS + h];
        dt = dtv[row * NHEADS + h];
        #pragma unroll
        for (int off = 1; off < 64; off <<= 1) {
            float u = __shfl_up(pv, off, 64);
            if ((tid & 63) >= off) pv += u;
        }
        if ((tid & 63) == 63) wsum[tid >> 6] = pv;
    }
    __syncthreads();
    if (tid < QCH) {
        float tot = wsum[0] + wsum[1];
        if (tid >= 64) pv += wsum[0];
        const size_t idx = ((size_t)bh * NCH + c) * QCH + tid;
        cabuf[idx] = pv;
        expca[idx] = expf(pv);
        dtbuf[idx] = dt;
        wsh[tid]   = expf(tot - pv) * dt;
        if (tid == 0) dtot[bh * NCH + c] = expf(tot);
    }
    __syncthreads();
    {
        const int f = tid & 127;
        const int jh = (tid >> 7) * 64;
        const ushort_t* xsrc = xcv + (row0 + jh) * DINNER + h * 128 + f;
        const ushort_t* bsrc = Bcg + (row0 + jh) * DSTATE + f;
        char* xrow = (char*)Xt + f * 256;
        char* brow = (char*)Bt + f * 256;
        #pragma unroll 2
        for (int e8 = 0; e8 < 8; e8++) {
            ushort8 tx, tb;
            #pragma unroll
            for (int e = 0; e < 8; e++) {
                int j = e8 * 8 + e;
                tx[e] = xsrc[(size_t)j * DINNER];
                tb[e] = f2bf(bf2f(bsrc[(size_t)j * DSTATE]) * wsh[jh + j]);
            }
            int cb = (jh + e8 * 8) * 2;
            *(ushort8*)(xrow + SWZ(f, cb)) = tx;
            *(ushort8*)(brow + SWZ(f, cb)) = tb;
        }
    }
    __syncthreads();
    const int lane = tid & 63, wave = tid >> 6;
    const int wp = (wave >> 1) * 64, wn = (wave & 1) * 64;
    const int fr = lane & 15, ko = (lane >> 4) * 8;
    f32x4 acc[4][4];
    #pragma unroll
    for (int i = 0; i < 4; i++)
        #pragma unroll
        for (int j = 0; j < 4; j++) acc[i][j] = (f32x4){0.f, 0.f, 0.f, 0.f};
    for (int k0 = 0; k0 < 128; k0 += 32) {
        bf16x8 af[4], bfr[4];
        #pragma unroll
        for (int i = 0; i < 4; i++) {
            int rp = wp + i * 16 + fr;
            af[i] = *(const bf16x8*)((const char*)Xt + rp * 256 + SWZ(rp, (k0 + ko) * 2));
        }
        #pragma unroll
        for (int j = 0; j < 4; j++) {
            int rn = wn + j * 16 + fr;
            bfr[j] = *(const bf16x8*)((const char*)Bt + rn * 256 + SWZ(rn, (k0 + ko) * 2));
        }
        #pragma unroll
        for (int i = 0; i < 4; i++)
            #pragma unroll
            for (int j = 0; j < 4; j++)
                acc[i][j] = __builtin_amdgcn_mfma_f32_16x16x32_bf16(af[i], bfr[j], acc[i][j], 0, 0, 0);
    }
    const int r0 = (lane >> 4) * 4;
    ushort_t* outp = states + ((size_t)bh * NCH + c) * 16384;
    #pragma unroll
    for (int i = 0; i < 4; i++)
        #pragma unroll
        for (int j = 0; j < 4; j++)
            #pragma unroll
            for (int r = 0; r < 4; r++)
                outp[(wp + i * 16 + r0 + r) * 128 + wn + j * 16 + fr] = f2bf(acc[i][j][r]);
}

// ---------------- inter-chunk state scan (full unroll: loads hoisted ahead of chain) ----------------
__global__ __launch_bounds__(256) void statescan_kernel(ushort_t* __restrict__ states,
        const float* __restrict__ dtot) {
    const int pseg = blockIdx.x, bh = blockIdx.y;
    const int tid = threadIdx.x;
    const int p = pseg * 8 + (tid >> 5);
    const int n4 = (tid & 31) * 4;
    ushort_t* base = states + (size_t)bh * NCH * 16384 + p * 128 + n4;
    const float* dtp = dtot + bh * NCH;
    ushortv4 cs[NCH];
    float dts[NCH];
    #pragma unroll
    for (int c = 0; c < NCH; c++) cs[c] = *(const ushortv4*)(base + (size_t)c * 16384);
    #pragma unroll
    for (int c = 0; c < NCH; c++) dts[c] = dtp[c];
    float r0 = 0.f, r1 = 0.f, r2 = 0.f, r3 = 0.f;
    #pragma unroll
    for (int c = 0; c < NCH; c++) {
        ushortv4 o;
        o[0] = f2bf(r0); o[1] = f2bf(r1); o[2] = f2bf(r2); o[3] = f2bf(r3);
        *(ushortv4*)(base + (size_t)c * 16384) = o;
        float d = dts[c];
        r0 = r0 * d + bf2f(cs[c][0]);
        r1 = r1 * d + bf2f(cs[c][1]);
        r2 = r2 * d + bf2f(cs[c][2]);
        r3 = r3 * d + bf2f(cs[c][3]);
    }
}

// ---------------- chunk output: y = exp(ca)*(C @ S_init) + (mask(CB^T) masked-decay) @ X ----------------
__global__ __launch_bounds__(256) void chunkout_kernel(const ushort_t* __restrict__ xcv,
        const ushort_t* __restrict__ Bcg, const ushort_t* __restrict__ Ccg,
        const ushort_t* __restrict__ states, const float* __restrict__ cabuf,
        const float* __restrict__ expca, const float* __restrict__ dtbuf,
        const float* __restrict__ Dvec, ushort_t* __restrict__ yv) {
    const int c = blockIdx.x, h = blockIdx.y, b = blockIdx.z;
    const int bh = b * NHEADS + h;
    const int tid = threadIdx.x;
    __shared__ ushort_t R1[128 * 128];   // ST -> B -> P
    __shared__ ushort_t R2[128 * 128];   // C -> Xt
    __shared__ float cash[QCH], dtsh[QCH], exsh[QCH];
    const size_t aidx = ((size_t)bh * NCH + c) * QCH;
    if (tid < QCH) {
        cash[tid] = cabuf[aidx + tid];
        dtsh[tid] = dtbuf[aidx + tid];
        exsh[tid] = expca[aidx + tid];
    }
    const size_t row0 = (size_t)b * SEQLEN + c * QCH;
    {
        const ushort_t* sp = states + ((size_t)bh * NCH + c) * 16384;
        #pragma unroll
        for (int it = 0; it < 8; it++) {
            int g = tid + it * 256;
            int r = g >> 4, n8 = (g & 15) * 8;
            ushort8 vc = *(const ushort8*)&Ccg[(row0 + r) * DSTATE + n8];
            ushort8 vs = *(const ushort8*)&sp[r * 128 + n8];
            int cb = n8 * 2;
            *(ushort8*)((char*)R2 + r * 256 + SWZ(r, cb)) = vc;
            *(ushort8*)((char*)R1 + r * 256 + SWZ(r, cb)) = vs;
        }
    }
    __syncthreads();
    const int lane = tid & 63, wave = tid >> 6;
    const int fr = lane & 15, ko = (lane >> 4) * 8, r0 = (lane >> 4) * 4;
    const int wty = (wave >> 1) * 64, wpy = (wave & 1) * 64;
    f32x4 y_[4][4];
    #pragma unroll
    for (int i = 0; i < 4; i++)
        #pragma unroll
        for (int j = 0; j < 4; j++) y_[i][j] = (f32x4){0.f, 0.f, 0.f, 0.f};
    for (int k0 = 0; k0 < 128; k0 += 32) {
        bf16x8 af[4], bfr[4];
        #pragma unroll
        for (int i = 0; i < 4; i++) {
            int rt = wty + i * 16 + fr;
            af[i] = *(const bf16x8*)((const char*)R2 + rt * 256 + SWZ(rt, (k0 + ko) * 2));
        }
        #pragma unroll
        for (int j = 0; j < 4; j++) {
            int rp = wpy + j * 16 + fr;
            bfr[j] = *(const bf16x8*)((const char*)R1 + rp * 256 + SWZ(rp, (k0 + ko) * 2));
        }
        #pragma unroll
        for (int i = 0; i < 4; i++)
            #pragma unroll
            for (int j = 0; j < 4; j++)
                y_[i][j] = __builtin_amdgcn_mfma_f32_16x16x32_bf16(af[i], bfr[j], y_[i][j], 0, 0, 0);
    }
    #pragma unroll
    for (int i = 0; i < 4; i++)
        #pragma unroll
        for (int r = 0; r < 4; r++) {
            float sc = exsh[wty + i * 16 + r0 + r];
            #pragma unroll
            for (int j = 0; j < 4; j++) y_[i][j][r] *= sc;
        }
    __syncthreads();
    #pragma unroll
    for (int it = 0; it < 8; it++) {
        int g = tid + it * 256;
        int r = g >> 4, n8 = (g & 15) * 8;
        ushort8 vb = *(const ushort8*)&Bcg[(row0 + r) * DSTATE + n8];
        *(ushort8*)((char*)R1 + r * 256 + SWZ(r, n8 * 2)) = vb;
    }
    __syncthreads();
    const int wj = (wave >> 1) * 64, wt = (wave & 1) * 64;
    f32x4 g_[4][4];
    #pragma unroll
    for (int i = 0; i < 4; i++)
        #pragma unroll
        for (int t = 0; t < 4; t++) g_[i][t] = (f32x4){0.f, 0.f, 0.f, 0.f};
    if (!(wj == 64 && wt == 0)) {
        for (int k0 = 0; k0 < 128; k0 += 32) {
            bf16x8 af[4], bfr[4];
            #pragma unroll
            for (int i = 0; i < 4; i++) {
                int rj = wj + i * 16 + fr;
                af[i] = *(const bf16x8*)((const char*)R1 + rj * 256 + SWZ(rj, (k0 + ko) * 2));
            }
            #pragma unroll
            for (int t = 0; t < 4; t++) {
                int rt = wt + t * 16 + fr;
                bfr[t] = *(const bf16x8*)((const char*)R2 + rt * 256 + SWZ(rt, (k0 + ko) * 2));
            }
            #pragma unroll
            for (int i = 0; i < 4; i++)
                #pragma unroll
                for (int t = 0; t < 4; t++)
                    g_[i][t] = __builtin_amdgcn_mfma_f32_16x16x32_bf16(af[i], bfr[t], g_[i][t], 0, 0, 0);
        }
    }
    __syncthreads();
    {
        const float Dh = Dvec[h];
        #pragma unroll
        for (int i = 0; i < 4; i++) {
            #pragma unroll
            for (int t = 0; t < 4; t++) {
                int tt = wt + t * 16 + fr;
                int jj0 = wj + i * 16 + r0;
                ushortv4 pk;
                #pragma unroll
                for (int r = 0; r < 4; r++) {
                    int jj = jj0 + r;
                    float val = 0.f;
                    if (jj <= tt) {
                        val = g_[i][t][r] * expf(cash[tt] - cash[jj]) * dtsh[jj];
                        if (jj == tt) val += Dh;
                    }
                    pk[r] = f2bf(val);
                }
                *(ushortv4*)((char*)R1 + tt * 256 + SWZ(tt, jj0 * 2)) = pk;
            }
        }
        const int f = tid & 127;
        const int jh = (tid >> 7) * 64;
        const ushort_t* xsrc = xcv + (row0 + jh) * DINNER + h * 128 + f;
        char* xrow = (char*)R2 + f * 256;
        #pragma unroll 2
        for (int e8 = 0; e8 < 8; e8++) {
            ushort8 tx;
            #pragma unroll
            for (int e = 0; e < 8; e++) tx[e] = xsrc[(size_t)(e8 * 8 + e) * DINNER];
            int cb = (jh + e8 * 8) * 2;
            *(ushort8*)(xrow + SWZ(f, cb)) = tx;
        }
    }
    __syncthreads();
    const int kmax = wty + 64;
    for (int k0 = 0; k0 < kmax; k0 += 32) {
        bf16x8 af[4], bfr[4];
        #pragma unroll
        for (int i = 0; i < 4; i++) {
            int rt = wty + i * 16 + fr;
            af[i] = *(const bf16x8*)((const char*)R1 + rt * 256 + SWZ(rt, (k0 + ko) * 2));
        }
        #pragma unroll
        for (int j = 0; j < 4; j++) {
            int rp = wpy + j * 16 + fr;
            bfr[j] = *(const bf16x8*)((const char*)R2 + rp * 256 + SWZ(rp, (k0 + ko) * 2));
        }
        #pragma unroll
        for (int i = 0; i < 4; i++)
            #pragma unroll
            for (int j = 0; j < 4; j++)
                y_[i][j] = __builtin_amdgcn_mfma_f32_16x16x32_bf16(af[i], bfr[j], y_[i][j], 0, 0, 0);
    }
    #pragma unroll
    for (int i = 0; i < 4; i++)
        #pragma unroll
        for (int j = 0; j < 4; j++)
            #pragma unroll
            for (int r = 0; r < 4; r++) {
                int t = wty + i * 16 + r0 + r;
                int p = wpy + j * 16 + fr;
                yv[(row0 + t) * DINNER + h * 128 + p] = f2bf(y_[i][j][r]);
            }
}

// ---------------- gate (y * silu(z)) + RMSNorm -> bf16 (z from bf16 zxb) ----------------
__global__ __launch_bounds__(256) void gate_rms(const ushort_t* __restrict__ yv,
        const ushort_t* __restrict__ zxb, const float* __restrict__ rms_w,
        ushort_t* __restrict__ ynorm) {
    int r = blockIdx.x, t = threadIdx.x;
    const ushort_t* yr = yv + (size_t)r * DINNER;
    const ushort_t* zr = zxb + (size_t)r * NPAD;
    ushort8 y8 = *(const ushort8*)&yr[t * 8];
    ushort8 z8 = *(const ushort8*)&zr[t * 8];
    float g[8];
    #pragma unroll
    for (int j = 0; j < 8; j++)
        g[j] = bf2f((ushort_t)y8[j]) * siluf(bf2f((ushort_t)z8[j]));
    float sq = 0.f;
    #pragma unroll
    for (int j = 0; j < 8; j++) sq += g[j] * g[j];
    __shared__ float red[4];
    #pragma unroll
    for (int m = 32; m >= 1; m >>= 1) sq += __shfl_xor(sq, m, 64);
    int wv = t >> 6;
    if ((t & 63) == 0) red[wv] = sq;
    __syncthreads();
    sq = red[0] + red[1] + red[2] + red[3];
    float scale = rsqrtf(sq * (1.f / DINNER) + EPSF);
    float4 w0 = *(const float4*)&rms_w[t * 8];
    float4 w1 = *(const float4*)&rms_w[t * 8 + 4];
    ushort8 o;
    o[0] = f2bf(g[0] * scale * w0.x);
    o[1] = f2bf(g[1] * scale * w0.y);
    o[2] = f2bf(g[2] * scale * w0.z);
    o[3] = f2bf(g[3] * scale * w0.w);
    o[4] = f2bf(g[4] * scale * w1.x);
    o[5] = f2bf(g[5] * scale * w1.y);
    o[6] = f2bf(g[6] * scale * w1.z);
    o[7] = f2bf(g[7] * scale * w1.w);
    *(ushort8*)&ynorm[(size_t)r * DINNER + t * 8] = o;
}

extern "C" void kernel_launch(void* const* d_in, const int* in_sizes, int n_in,
                              void* d_out, int out_size, void* d_ws, size_t ws_size,
                              hipStream_t stream) {
    (void)in_sizes; (void)n_in; (void)out_size; (void)ws_size;
    const float* x       = (const float*)d_in[0];
    const float* ln_w    = (const float*)d_in[1];
    const float* ln_b    = (const float*)d_in[2];
    const float* W_in    = (const float*)d_in[3];
    const float* conv_w  = (const float*)d_in[4];
    const float* conv_b  = (const float*)d_in[5];
    const float* dt_bias = (const float*)d_in[6];
    const float* A_log   = (const float*)d_in[7];
    const float* Dvec    = (const float*)d_in[8];
    const float* rms_w   = (const float*)d_in[9];
    const float* W_out   = (const float*)d_in[10];
    float* out = (float*)d_out;

    char* ws = (char*)d_ws;
    size_t off = 0;
    auto alloc = [&](size_t bytes) -> void* {
        void* p = ws + off;
        off += (bytes + 255) & ~(size_t)255;
        return p;
    };
    ushort_t* xn    = (ushort_t*)alloc((size_t)BL * DMODEL * 2);
    ushort_t* WinT  = (ushort_t*)alloc((size_t)NPAD * DMODEL * 2);
    ushort_t* zxb   = (ushort_t*)alloc((size_t)BL * NPAD * 2);
    ushort_t* xcv   = (ushort_t*)alloc((size_t)BL * DINNER * 2);
    ushort_t* Bcg   = (ushort_t*)alloc((size_t)BL * DSTATE * 2);
    ushort_t* Ccg   = (ushort_t*)alloc((size_t)BL * DSTATE * 2);
    float*    dtv   = (float*)   alloc((size_t)BL * NHEADS * 4);
    float*    dta   = (float*)   alloc((size_t)BL * NHEADS * 4);
    ushort_t* yv    = (ushort_t*)alloc((size_t)BL * DINNER * 2);
    ushort_t* ynorm = (ushort_t*)alloc((size_t)BL * DINNER * 2);
    ushort_t* WoutT = (ushort_t*)alloc((size_t)DMODEL * DINNER * 2);
    float*    wtr   = (float*)   alloc((size_t)4 * DXBC * 4);
    float*    cabuf = (float*)   alloc((size_t)BH * NCH * QCH * 4);
    float*    expcb = (float*)   alloc((size_t)BH * NCH * QCH * 4);
    float*    dtbuf = (float*)   alloc((size_t)BH * NCH * QCH * 4);
    float*    dtot  = (float*)   alloc((size_t)BH * NCH * 4);
    ushort_t* states= (ushort_t*)alloc((size_t)BH * NCH * 16384 * 2);

    ln_kernel<<<BL, 256, 0, stream>>>(x, ln_w, ln_b, xn);
    prep_kernel<<<NB_WIN + NB_WOUT + (DXBC + 255) / 256, 256, 0, stream>>>(
        W_in, W_out, conv_w, WinT, WoutT, wtr);
    gemm_bt<true><<<(NPAD / 128) * (BL / 128), 256, 0, stream>>>(xn, WinT, zxb, nullptr, DMODEL, NPAD, NPAD / 128);
    conv_kernel<<<BL / 8, 256, 0, stream>>>(zxb, wtr, conv_b, dt_bias, A_log, xcv, Bcg, Ccg, dtv, dta);
    chunkstate_kernel<<<dim3(NCH, NHEADS, BATCH), 256, 0, stream>>>(
        xcv, Bcg, dta, dtv, cabuf, expcb, dtbuf, dtot, states);
    statescan_kernel<<<dim3(16, BH), 256, 0, stream>>>(states, dtot);
    chunkout_kernel<<<dim3(NCH, NHEADS, BATCH), 256, 0, stream>>>(xcv, Bcg, Ccg, states, cabuf, expcb, dtbuf, Dvec, yv);
    gate_rms<<<BL, 256, 0, stream>>>(yv, zxb, rms_w, ynorm);
    gemm_bt<false><<<(DMODEL / 128) * (BL / 128), 256, 0, stream>>>(ynorm, WoutT, out, x, DINNER, DMODEL, DMODEL / 128);
}